// Round 1
// baseline (1180.807 us; speedup 1.0000x reference)
//
#include <hip/hip_runtime.h>
#include <hip/hip_bf16.h>
#include <stdint.h>
#include <string.h>

#define N_NODES 500000
#define N_EDGES 1000000
#define BATCH   4096
#define KNBR    20
#define DN      172
#define DT      100
#define DOUT    128

#define KPAD    192
#define KSTEPS  6     // 192 / 32
#define NCT     8     // 128 / 16 col tiles

typedef __attribute__((ext_vector_type(8))) short   bf16x8;
typedef __attribute__((ext_vector_type(4))) float   f32x4;
typedef __attribute__((ext_vector_type(2))) float   f32x2;

#define INV2PI 0.15915494309189535f

__device__ inline short f2bf(float f) {
    __hip_bfloat16 h = __float2bfloat16(f);
    short s;
    memcpy(&s, &h, 2);
    return s;
}

// ---------------------------------------------------------------------------
// Prep: build pre-arranged B-fragment arrays for W_node / W_edge (bf16), and
// the constant t=0 time embedding tconst = cos(phase) @ W_time + b_time.
// Fragment layout for mfma_f32_16x16x32_bf16 B-operand:
//   slot (ct, s, lane): col = ct*16 + (lane&15), k = s*32 + (lane>>4)*8 + j
// ---------------------------------------------------------------------------
__global__ void k_prep(const float* __restrict__ Wn, const float* __restrict__ We,
                       const float* __restrict__ Wt, const float* __restrict__ bt,
                       const float* __restrict__ tp,
                       short* __restrict__ wnF, short* __restrict__ weF,
                       float* __restrict__ tconst)
{
    const int tid = threadIdx.x;
    const int NSLOT = NCT * KSTEPS * 64;
    for (int idx = tid; idx < 2 * NSLOT; idx += blockDim.x) {
        int m    = idx / NSLOT;
        int slot = idx % NSLOT;
        int ct   = slot / (KSTEPS * 64);
        int rem  = slot % (KSTEPS * 64);
        int s    = rem / 64;
        int l    = rem % 64;
        int col   = ct * 16 + (l & 15);
        int kbase = s * 32 + (l >> 4) * 8;
        const float* W = m ? We : Wn;
        bf16x8 sv;
        #pragma unroll
        for (int j = 0; j < 8; ++j) {
            int k = kbase + j;
            float f = (k < DN) ? W[k * DOUT + col] : 0.0f;
            sv[j] = f2bf(f);
        }
        *(bf16x8*)((m ? weF : wnF) + (size_t)slot * 8) = sv;
    }
    if (tid < DOUT) {
        float acc = bt[tid];
        for (int j = 0; j < DT; ++j)
            acc += cosf(tp[j]) * Wt[j * DOUT + tid];
        tconst[tid] = acc;
    }
}

// ---------------------------------------------------------------------------
// Projection GEMM: out[r][c] = feat[r][:DN] @ W[:,c] + bias[c], bf16 output.
// 64 rows x 128 cols per block (4 waves, 16 rows each), K padded to 192.
// ---------------------------------------------------------------------------
__global__ __launch_bounds__(256, 2)
void k_proj(const float* __restrict__ feat, const float* __restrict__ bias,
            const short* __restrict__ wfrag, short* __restrict__ out, int nrows)
{
    __shared__ __attribute__((aligned(16))) short lds_b[NCT * KSTEPS * 64 * 8];  // 48 KB
    __shared__ __attribute__((aligned(16))) short lds_a[4 * KSTEPS * 64 * 8];    // 24 KB

    const int tid  = threadIdx.x;
    const int lane = tid & 63;
    const int wv   = tid >> 6;
    const int row0 = blockIdx.x * 64;

    // stage B fragments (linear 48 KB copy)
    {
        const f32x4* src = (const f32x4*)wfrag;
        f32x4*       dst = (f32x4*)lds_b;
        #pragma unroll
        for (int i = 0; i < 12; ++i)               // 3072 chunks / 256 threads
            dst[tid + i * 256] = src[tid + i * 256];
    }
    // stage A fragments: 64 rows x 24 k-octets
    #pragma unroll
    for (int it = 0; it < 6; ++it) {
        int t   = tid + it * 256;
        int rl  = t / 24, oct = t % 24;
        int grow = row0 + rl;
        float v[8] = {0, 0, 0, 0, 0, 0, 0, 0};
        if (grow < nrows) {
            int k0 = oct * 8;
            if (k0 < DN) {
                f32x4 a = *(const f32x4*)(feat + (size_t)grow * DN + k0);
                v[0] = a[0]; v[1] = a[1]; v[2] = a[2]; v[3] = a[3];
                if (k0 + 4 < DN) {
                    f32x4 b = *(const f32x4*)(feat + (size_t)grow * DN + k0 + 4);
                    v[4] = b[0]; v[5] = b[1]; v[6] = b[2]; v[7] = b[3];
                }
            }
        }
        bf16x8 sv;
        #pragma unroll
        for (int j = 0; j < 8; ++j) sv[j] = f2bf(v[j]);
        int rt = rl >> 4, r15 = rl & 15, s = oct >> 2, lsub = oct & 3;
        *(bf16x8*)&lds_a[((size_t)((rt * KSTEPS + s) * 64 + (r15 + 16 * lsub))) * 8] = sv;
    }
    __syncthreads();

    f32x4 acc[NCT];
    #pragma unroll
    for (int ct = 0; ct < NCT; ++ct) acc[ct] = (f32x4){0, 0, 0, 0};

    #pragma unroll
    for (int s = 0; s < KSTEPS; ++s) {
        bf16x8 a = *(const bf16x8*)&lds_a[((size_t)((wv * KSTEPS + s) * 64 + lane)) * 8];
        #pragma unroll
        for (int ct = 0; ct < NCT; ++ct) {
            bf16x8 b = *(const bf16x8*)&lds_b[((size_t)((ct * KSTEPS + s) * 64 + lane)) * 8];
            acc[ct] = __builtin_amdgcn_mfma_f32_16x16x32_bf16(a, b, acc[ct], 0, 0, 0);
        }
    }

    // C/D layout: col = lane&15, row = (lane>>4)*4 + reg  [m89-verified]
    const int rbase = row0 + wv * 16 + (lane >> 4) * 4;
    const int c0    = lane & 15;
    #pragma unroll
    for (int ct = 0; ct < NCT; ++ct) {
        int c = ct * 16 + c0;
        float bs = bias[c];
        #pragma unroll
        for (int r = 0; r < 4; ++r) {
            int grow = rbase + r;
            if (grow < nrows)
                out[(size_t)grow * DOUT + c] = f2bf(acc[ct][r] + bs);
        }
    }
}

// ---------------------------------------------------------------------------
// Fused message-passing layer. One wave per output row.
//   out[n] = src + tconst + (sum_valid(nbr + t_emb + e_feat)) / max(cnt,1)
// t_emb sum collapsed: (sum_valid cos_vec) @ W_time + cnt*b_time.
// L2NBR=false: nbr rows gathered from node_proj (bf16).
// L2NBR=true : nbr rows from contiguous f32 emb1.
// ---------------------------------------------------------------------------
template <bool L2NBR>
__global__ __launch_bounds__(256)
void k_layer(const short* __restrict__ node_proj, const short* __restrict__ edge_proj,
             const float* __restrict__ nbr_f32,
             const int* __restrict__ src_idx,
             const float* __restrict__ ts_arr, int ts_div,
             const int* __restrict__ nbrs, const int* __restrict__ eidx,
             const float* __restrict__ etime,
             const float* __restrict__ Wt, const float* __restrict__ bt,
             const float* __restrict__ tw, const float* __restrict__ tp,
             const float* __restrict__ tconst,
             float* __restrict__ outp, int nrows)
{
    __shared__ __attribute__((aligned(16))) float lds_wt[DT * DOUT];  // 51.2 KB
    __shared__ float lds_cs[4][112];

    const int tid = threadIdx.x, lane = tid & 63, wv = tid >> 6;

    // stage W_time (f32) into LDS once per block
    #pragma unroll
    for (int i = 0; i < 13; ++i) {
        int idx = tid + i * 256;
        if (idx < DT * DOUT / 4)
            ((f32x4*)lds_wt)[idx] = ((const f32x4*)Wt)[idx];
    }
    __syncthreads();

    const int row = blockIdx.x * 4 + wv;

    int   nb = 0, ei = 0;
    float et = 0.0f;
    if (lane < KNBR) {
        nb = nbrs[(size_t)row * KNBR + lane];
        ei = eidx[(size_t)row * KNBR + lane];
        et = etime[(size_t)row * KNBR + lane];
    }
    const unsigned long long vm = __ballot(lane < KNBR && nb != 0);
    const int   cnt = __popcll(vm);
    const float ts  = ts_arr[row / ts_div];

    // per-lane time params: j0 = lane, j1 = lane + 64 (lanes 0..35)
    float wr0 = tw[lane] * INV2PI;
    float pr0 = tp[lane] * INV2PI;
    float wr1 = 0.0f, pr1 = 0.0f;
    if (lane < DT - 64) { wr1 = tw[64 + lane] * INV2PI; pr1 = tp[64 + lane] * INV2PI; }

    float cs0 = 0.0f, cs1 = 0.0f;
    #pragma unroll
    for (int k = 0; k < KNBR; ++k) {
        if ((vm >> k) & 1ull) {
            float d  = ts - __shfl(et, k);
            float r0 = d * wr0 + pr0; r0 -= floorf(r0);
            float r1 = d * wr1 + pr1; r1 -= floorf(r1);
            cs0 += __builtin_amdgcn_cosf(r0);
            cs1 += __builtin_amdgcn_cosf(r1);
        }
    }
    lds_cs[wv][lane] = cs0;
    if (lane < DT - 64) lds_cs[wv][64 + lane] = cs1;

    // gather + sum messages; this thread owns dims d2, d2+1
    const int d2 = lane * 2;
    float ms0 = 0.0f, ms1 = 0.0f;
    #pragma unroll
    for (int k = 0; k < KNBR; ++k) {
        if ((vm >> k) & 1ull) {
            int e = __shfl(ei, k);
            uint32_t ev = *(const uint32_t*)(edge_proj + (size_t)e * DOUT + d2);
            ms0 += __uint_as_float(ev << 16);
            ms1 += __uint_as_float(ev & 0xffff0000u);
            if (L2NBR) {
                f32x2 nv = *(const f32x2*)(nbr_f32 + ((size_t)row * KNBR + k) * DOUT + d2);
                ms0 += nv[0]; ms1 += nv[1];
            } else {
                int n = __shfl(nb, k);
                uint32_t nv = *(const uint32_t*)(node_proj + (size_t)n * DOUT + d2);
                ms0 += __uint_as_float(nv << 16);
                ms1 += __uint_as_float(nv & 0xffff0000u);
            }
        }
    }

    // time matvec: csum[100] @ W_time[:, d2:d2+2]
    float tg0 = 0.0f, tg1 = 0.0f;
    #pragma unroll 4
    for (int j = 0; j < DT; ++j) {
        float c  = lds_cs[wv][j];
        f32x2 w2 = *(const f32x2*)&lds_wt[j * DOUT + d2];
        tg0 += c * w2[0];
        tg1 += c * w2[1];
    }

    const float fc   = (float)cnt;
    const float cntf = (cnt > 0) ? fc : 1.0f;
    const float inv  = 1.0f / cntf;
    f32x2 bt2 = *(const f32x2*)&bt[d2];
    f32x2 tc2 = *(const f32x2*)&tconst[d2];
    int   si  = src_idx[row];
    uint32_t sv = *(const uint32_t*)(node_proj + (size_t)si * DOUT + d2);
    float s0 = __uint_as_float(sv << 16);
    float s1 = __uint_as_float(sv & 0xffff0000u);

    float o0 = s0 + tc2[0] + (ms0 + tg0 + fc * bt2[0]) * inv;
    float o1 = s1 + tc2[1] + (ms1 + tg1 + fc * bt2[1]) * inv;
    *(f32x2*)(outp + (size_t)row * DOUT + d2) = (f32x2){o0, o1};
}

// ---------------------------------------------------------------------------
extern "C" void kernel_launch(void* const* d_in, const int* in_sizes, int n_in,
                              void* d_out, int out_size, void* d_ws, size_t ws_size,
                              hipStream_t stream)
{
    const float* node_features = (const float*)d_in[0];
    const float* edge_features = (const float*)d_in[1];
    const float* W_node  = (const float*)d_in[2];
    const float* b_node  = (const float*)d_in[3];
    const float* W_time  = (const float*)d_in[4];
    const float* b_time  = (const float*)d_in[5];
    const float* W_edge  = (const float*)d_in[6];
    const float* b_edge  = (const float*)d_in[7];
    const float* time_w  = (const float*)d_in[8];
    const float* time_ph = (const float*)d_in[9];
    const int*   source_nodes = (const int*)d_in[10];
    const float* timestamps   = (const float*)d_in[11];
    const int*   nbrs_l2  = (const int*)d_in[12];
    const int*   eidx_l2  = (const int*)d_in[13];
    const float* etime_l2 = (const float*)d_in[14];
    const int*   nbrs_l1  = (const int*)d_in[15];
    const int*   eidx_l1  = (const int*)d_in[16];
    const float* etime_l1 = (const float*)d_in[17];

    // workspace layout (256B aligned)
    char*  ws        = (char*)d_ws;
    short* node_proj = (short*)(ws);                  // 500000*128*2 = 128,000,000
    short* edge_proj = (short*)(ws + 128000000);      // 1M*128*2     = 256,000,000
    float* emb1      = (float*)(ws + 384000000);      // 81920*128*4  =  41,943,040
    float* tconst    = (float*)(ws + 425943040);      // 512
    short* wnF       = (short*)(ws + 425943552);      // 49152
    short* weF       = (short*)(ws + 425992704);      // 49152
    if (ws_size < 426100000ull) return;               // insufficient scratch

    k_prep<<<1, 256, 0, stream>>>(W_node, W_edge, W_time, b_time, time_ph,
                                  wnF, weF, tconst);

    k_proj<<<(N_NODES + 63) / 64, 256, 0, stream>>>(node_features, b_node, wnF,
                                                    node_proj, N_NODES);
    k_proj<<<(N_EDGES + 63) / 64, 256, 0, stream>>>(edge_features, b_edge, weF,
                                                    edge_proj, N_EDGES);

    // layer 1: rows = B*K, nbr rows gathered from node_proj
    k_layer<false><<<(BATCH * KNBR) / 4, 256, 0, stream>>>(
        node_proj, edge_proj, nullptr, nbrs_l2,
        timestamps, KNBR, nbrs_l1, eidx_l1, etime_l1,
        W_time, b_time, time_w, time_ph, tconst, emb1, BATCH * KNBR);

    // layer 2: rows = B, nbr rows from contiguous emb1 (f32), output f32
    k_layer<true><<<BATCH / 4, 256, 0, stream>>>(
        node_proj, edge_proj, emb1, source_nodes,
        timestamps, 1, nbrs_l2, eidx_l2, etime_l2,
        W_time, b_time, time_w, time_ph, tconst, (float*)d_out, BATCH);
}

// Round 3
// 842.558 us; speedup vs baseline: 1.4015x; 1.4015x over previous
//
#include <hip/hip_runtime.h>
#include <hip/hip_bf16.h>
#include <stdint.h>
#include <string.h>

#define N_NODES 500000
#define N_EDGES 1000000
#define BATCH   4096
#define KNBR    20
#define DN      172
#define DT      100
#define DOUT    128

#define KSTEPS   6    // ceil(172/32)
#define KSTEPS_T 4    // ceil(100/32) padded to 128
#define NCT      8    // 128 / 16 col tiles
#define CSW      112  // csum row width (bf16), 224 B, 16B-aligned

typedef __attribute__((ext_vector_type(8))) short   bf16x8;
typedef __attribute__((ext_vector_type(4))) float   f32x4;
typedef __attribute__((ext_vector_type(2))) float   f32x2;

#define INV2PI 0.15915494309189535f

__device__ inline short f2bf(float f) {
    __hip_bfloat16 h = __float2bfloat16(f);
    short s;
    memcpy(&s, &h, 2);
    return s;
}
__device__ inline float bflo(uint32_t u) { return __uint_as_float(u << 16); }
__device__ inline float bfhi(uint32_t u) { return __uint_as_float(u & 0xffff0000u); }

// ---------------------------------------------------------------------------
// Prep: B-fragment arrays for W_node / W_edge (KSTEPS) and W_time (KSTEPS_T),
// plus tconst = cos(phase) @ W_time + b_time.
// B-frag slot (ct, s, lane): col = ct*16 + (lane&15), k = s*32 + (lane>>4)*8 + j
// ---------------------------------------------------------------------------
__global__ void k_prep(const float* __restrict__ Wn, const float* __restrict__ We,
                       const float* __restrict__ Wt, const float* __restrict__ bt,
                       const float* __restrict__ tp,
                       short* __restrict__ wnF, short* __restrict__ weF,
                       short* __restrict__ wtF, float* __restrict__ tconst)
{
    const int tid = threadIdx.x;
    const int NS6 = NCT * KSTEPS * 64;
    const int NS4 = NCT * KSTEPS_T * 64;
    for (int idx = tid; idx < 2 * NS6 + NS4; idx += blockDim.x) {
        const float* W;
        short* dst;
        int slot, ks;
        if (idx < NS6)            { W = Wn; dst = wnF; slot = idx;           ks = KSTEPS; }
        else if (idx < 2 * NS6)   { W = We; dst = weF; slot = idx - NS6;     ks = KSTEPS; }
        else                      { W = Wt; dst = wtF; slot = idx - 2 * NS6; ks = KSTEPS_T; }
        int kd = (ks == KSTEPS) ? DN : DT;
        int ct  = slot / (ks * 64);
        int rem = slot % (ks * 64);
        int s   = rem / 64;
        int l   = rem % 64;
        int col   = ct * 16 + (l & 15);
        int kbase = s * 32 + (l >> 4) * 8;
        bf16x8 sv;
        #pragma unroll
        for (int j = 0; j < 8; ++j) {
            int k = kbase + j;
            sv[j] = f2bf((k < kd) ? W[k * DOUT + col] : 0.0f);
        }
        *(bf16x8*)(dst + (size_t)slot * 8) = sv;
    }
    if (tid < DOUT) {
        float acc = bt[tid];
        for (int j = 0; j < DT; ++j)
            acc += cosf(tp[j]) * Wt[j * DOUT + tid];
        tconst[tid] = acc;
    }
}

// ---------------------------------------------------------------------------
// Projection GEMM: out[r][c] = feat[r][:DN] @ W[:,c] + bias[c], bf16 out.
// 4 waves x 16 rows = 64 rows/block. A-frags loaded DIRECTLY from global:
// lane l reads row (l&15), k = s*32+(l>>4)*8 .. +8  -> 16 rows x 128B per
// k-step, fully coalesced. No LDS A-stage, no per-tile sync.
// ---------------------------------------------------------------------------
__global__ __launch_bounds__(256)
void k_proj(const float* __restrict__ feat, const float* __restrict__ bias,
            const short* __restrict__ wfrag, short* __restrict__ out,
            int nrows, int ntiles)
{
    __shared__ __attribute__((aligned(16))) short lds_b[NCT * KSTEPS * 64 * 8];  // 48 KB
    const int tid = threadIdx.x, lane = tid & 63, wv = tid >> 6;

    #pragma unroll
    for (int i = 0; i < 12; ++i)
        ((f32x4*)lds_b)[tid + i * 256] = ((const f32x4*)wfrag)[tid + i * 256];
    __syncthreads();

    const int r15 = lane & 15, kq = lane >> 4, c0 = lane & 15;
    float bs[NCT];
    #pragma unroll
    for (int ct = 0; ct < NCT; ++ct) bs[ct] = bias[ct * 16 + c0];

    for (int tile = blockIdx.x; tile < ntiles; tile += gridDim.x) {
        const int row0 = tile * 64 + wv * 16;
        int r = row0 + r15;
        if (r > nrows - 1) r = nrows - 1;
        const float* fp = feat + (size_t)r * DN;

        f32x4 acc[NCT];
        #pragma unroll
        for (int ct = 0; ct < NCT; ++ct) acc[ct] = (f32x4){0, 0, 0, 0};

        #pragma unroll
        for (int s = 0; s < KSTEPS; ++s) {
            const int k0 = s * 32 + kq * 8;
            float v[8] = {0, 0, 0, 0, 0, 0, 0, 0};
            if (k0 + 8 <= DN) {
                f32x4 lo = *(const f32x4*)(fp + k0);
                f32x4 hi = *(const f32x4*)(fp + k0 + 4);
                v[0]=lo[0]; v[1]=lo[1]; v[2]=lo[2]; v[3]=lo[3];
                v[4]=hi[0]; v[5]=hi[1]; v[6]=hi[2]; v[7]=hi[3];
            } else if (k0 < DN) {
                f32x4 lo = *(const f32x4*)(fp + k0);
                v[0]=lo[0]; v[1]=lo[1]; v[2]=lo[2]; v[3]=lo[3];
            }
            bf16x8 a;
            #pragma unroll
            for (int j = 0; j < 8; ++j) a[j] = f2bf(v[j]);
            #pragma unroll
            for (int ct = 0; ct < NCT; ++ct) {
                bf16x8 b = *(const bf16x8*)&lds_b[((ct * KSTEPS + s) * 64 + lane) * 8];
                acc[ct] = __builtin_amdgcn_mfma_f32_16x16x32_bf16(a, b, acc[ct], 0, 0, 0);
            }
        }
        const int rbase = row0 + (lane >> 4) * 4;
        #pragma unroll
        for (int ct = 0; ct < NCT; ++ct) {
            const int c = ct * 16 + c0;
            #pragma unroll
            for (int rr = 0; rr < 4; ++rr) {
                int grow = rbase + rr;
                if (grow < nrows)
                    out[(size_t)grow * DOUT + c] = f2bf(acc[ct][rr] + bs[ct]);
            }
        }
    }
}

// ---------------------------------------------------------------------------
// Gather layer (no LDS). One wave per output row. All 40 gather loads issued
// unconditionally up-front (max MLP); validity handled by fma(w, ., .).
// Writes: partial = src + tconst + (msg_sum + cnt*b_time)/cnt   (bf16 or f32)
//         csum'   = (sum_valid cos_vec) / cnt  as bf16, CSW-wide, zero-padded.
// Time matvec deferred to k_tgemm.
// ---------------------------------------------------------------------------
template <bool L2>
__global__ __launch_bounds__(256)
void k_gather(const short* __restrict__ node_proj, const short* __restrict__ edge_proj,
              const short* __restrict__ nbr_tab,
              const int* __restrict__ src_idx, const float* __restrict__ ts_arr,
              const int* __restrict__ nbrs, const int* __restrict__ eidx,
              const float* __restrict__ etime,
              const float* __restrict__ bt, const float* __restrict__ tw,
              const float* __restrict__ tp, const float* __restrict__ tconst,
              float* __restrict__ partial_f32, short* __restrict__ partial_bf16,
              short* __restrict__ csum_out)
{
    const int tid = threadIdx.x, lane = tid & 63, wv = tid >> 6;
    const int row = blockIdx.x * 4 + wv;

    int nb = 0, ei = 0;
    float et = 0.0f;
    if (lane < KNBR) {
        nb = nbrs[(size_t)row * KNBR + lane];
        ei = eidx[(size_t)row * KNBR + lane];
        et = etime[(size_t)row * KNBR + lane];
    }
    const unsigned long long vm = __ballot(lane < KNBR && nb != 0);
    const int   cnt = __popcll(vm);
    const float ts  = L2 ? ts_arr[row] : ts_arr[row / KNBR];

    int   ek[KNBR], nk[KNBR];
    float dk[KNBR];
    #pragma unroll
    for (int k = 0; k < KNBR; ++k) ek[k] = __shfl(ei, k);
    #pragma unroll
    for (int k = 0; k < KNBR; ++k) dk[k] = ts - __shfl(et, k);
    if (!L2) {
        #pragma unroll
        for (int k = 0; k < KNBR; ++k) nk[k] = __shfl(nb, k);
    }

    const int d2 = lane * 2;
    uint32_t ev[KNBR], nv[KNBR];
    #pragma unroll
    for (int k = 0; k < KNBR; ++k)
        ev[k] = *(const uint32_t*)(edge_proj + (size_t)ek[k] * DOUT + d2);
    #pragma unroll
    for (int k = 0; k < KNBR; ++k) {
        size_t ri = L2 ? ((size_t)row * KNBR + k) : (size_t)nk[k];
        nv[k] = *(const uint32_t*)(nbr_tab + ri * DOUT + d2);
    }

    const float wr0 = tw[lane] * INV2PI;
    const float pr0 = tp[lane] * INV2PI;
    float wr1 = 0.0f, pr1 = 0.0f;
    if (lane < DT - 64) { wr1 = tw[64 + lane] * INV2PI; pr1 = tp[64 + lane] * INV2PI; }

    float cs0 = 0, cs1 = 0, ms0 = 0, ms1 = 0;
    #pragma unroll
    for (int k = 0; k < KNBR; ++k) {
        const float w = (float)(int)((vm >> k) & 1ull);
        float r0 = dk[k] * wr0 + pr0; r0 -= floorf(r0);
        float r1 = dk[k] * wr1 + pr1; r1 -= floorf(r1);
        cs0 = fmaf(w, __builtin_amdgcn_cosf(r0), cs0);
        cs1 = fmaf(w, __builtin_amdgcn_cosf(r1), cs1);
        ms0 = fmaf(w, bflo(ev[k]) + bflo(nv[k]), ms0);
        ms1 = fmaf(w, bfhi(ev[k]) + bfhi(nv[k]), ms1);
    }

    const float fc  = (float)cnt;
    const float inv = (cnt > 0) ? 1.0f / fc : 1.0f;

    csum_out[(size_t)row * CSW + lane] = f2bf(cs0 * inv);
    if (lane < 48)
        csum_out[(size_t)row * CSW + 64 + lane] = f2bf(lane < DT - 64 ? cs1 * inv : 0.0f);

    const int si = src_idx[row];
    const uint32_t sv = *(const uint32_t*)(node_proj + (size_t)si * DOUT + d2);
    const f32x2 bt2 = *(const f32x2*)&bt[d2];
    const f32x2 tc2 = *(const f32x2*)&tconst[d2];
    const float o0 = bflo(sv) + tc2[0] + (ms0 + fc * bt2[0]) * inv;
    const float o1 = bfhi(sv) + tc2[1] + (ms1 + fc * bt2[1]) * inv;
    if (L2) {
        *(f32x2*)(partial_f32 + (size_t)row * DOUT + d2) = (f32x2){o0, o1};
    } else {
        uint32_t u = (uint32_t)(uint16_t)f2bf(o0) | ((uint32_t)(uint16_t)f2bf(o1) << 16);
        *(uint32_t*)(partial_bf16 + (size_t)row * DOUT + d2) = u;
    }
}

// ---------------------------------------------------------------------------
// Time GEMM: io[row][c] += csum'[row][:] @ W_time[:,c]   (in-place RMW).
// csum' is bf16, CSW-wide, zero-padded -> A-frags direct-loaded, no bounds.
// ---------------------------------------------------------------------------
template <bool F32IO>
__global__ __launch_bounds__(256)
void k_tgemm(const short* __restrict__ csum, const short* __restrict__ wtF,
             float* __restrict__ io_f32, short* __restrict__ io_bf16,
             int nrows, int ntiles)
{
    __shared__ __attribute__((aligned(16))) short lds_b[NCT * KSTEPS_T * 64 * 8];  // 32 KB
    const int tid = threadIdx.x, lane = tid & 63, wv = tid >> 6;

    #pragma unroll
    for (int i = 0; i < 8; ++i)
        ((f32x4*)lds_b)[tid + i * 256] = ((const f32x4*)wtF)[tid + i * 256];
    __syncthreads();

    const int r15 = lane & 15, kq = lane >> 4, c0 = lane & 15;

    for (int tile = blockIdx.x; tile < ntiles; tile += gridDim.x) {
        const int row0 = tile * 64 + wv * 16;
        int r = row0 + r15;
        if (r > nrows - 1) r = nrows - 1;
        const short* ap = csum + (size_t)r * CSW;

        f32x4 acc[NCT];
        #pragma unroll
        for (int ct = 0; ct < NCT; ++ct) acc[ct] = (f32x4){0, 0, 0, 0};

        #pragma unroll
        for (int s = 0; s < KSTEPS_T; ++s) {
            const int k0 = s * 32 + kq * 8;
            bf16x8 a = (bf16x8)(short)0;
            if (k0 + 8 <= CSW) a = *(const bf16x8*)(ap + k0);
            #pragma unroll
            for (int ct = 0; ct < NCT; ++ct) {
                bf16x8 b = *(const bf16x8*)&lds_b[((ct * KSTEPS_T + s) * 64 + lane) * 8];
                acc[ct] = __builtin_amdgcn_mfma_f32_16x16x32_bf16(a, b, acc[ct], 0, 0, 0);
            }
        }
        const int rbase = row0 + (lane >> 4) * 4;
        #pragma unroll
        for (int ct = 0; ct < NCT; ++ct) {
            const int c = ct * 16 + c0;
            #pragma unroll
            for (int rr = 0; rr < 4; ++rr) {
                int grow = rbase + rr;
                if (grow < nrows) {
                    size_t off = (size_t)grow * DOUT + c;
                    if (F32IO) {
                        io_f32[off] += acc[ct][rr];
                    } else {
                        float oldv = bflo((uint32_t)(uint16_t)io_bf16[off]);
                        io_bf16[off] = f2bf(oldv + acc[ct][rr]);
                    }
                }
            }
        }
    }
}

// ---------------------------------------------------------------------------
extern "C" void kernel_launch(void* const* d_in, const int* in_sizes, int n_in,
                              void* d_out, int out_size, void* d_ws, size_t ws_size,
                              hipStream_t stream)
{
    const float* node_features = (const float*)d_in[0];
    const float* edge_features = (const float*)d_in[1];
    const float* W_node  = (const float*)d_in[2];
    const float* b_node  = (const float*)d_in[3];
    const float* W_time  = (const float*)d_in[4];
    const float* b_time  = (const float*)d_in[5];
    const float* W_edge  = (const float*)d_in[6];
    const float* b_edge  = (const float*)d_in[7];
    const float* time_w  = (const float*)d_in[8];
    const float* time_ph = (const float*)d_in[9];
    const int*   source_nodes = (const int*)d_in[10];
    const float* timestamps   = (const float*)d_in[11];
    const int*   nbrs_l2  = (const int*)d_in[12];
    const int*   eidx_l2  = (const int*)d_in[13];
    const float* etime_l2 = (const float*)d_in[14];
    const int*   nbrs_l1  = (const int*)d_in[15];
    const int*   eidx_l1  = (const int*)d_in[16];
    const float* etime_l1 = (const float*)d_in[17];

    // workspace layout (all offsets 256B-aligned)
    char*  ws        = (char*)d_ws;
    short* node_proj = (short*)(ws);                    // 128,000,000
    short* edge_proj = (short*)(ws + 128000000);        // 256,000,000
    short* emb1      = (short*)(ws + 384000000);        //  20,971,520 (bf16)
    short* csum1     = (short*)(ws + 404971520);        //  18,350,080
    short* csum2     = (short*)(ws + 423321600);        //     917,504
    float* tconst    = (float*)(ws + 424239104);        //         512
    short* wnF       = (short*)(ws + 424239616);        //      49,152
    short* weF       = (short*)(ws + 424288768);        //      49,152
    short* wtF       = (short*)(ws + 424337920);        //      32,768 -> 424,370,688
    if (ws_size < 424400000ull) return;

    k_prep<<<1, 256, 0, stream>>>(W_node, W_edge, W_time, b_time, time_ph,
                                  wnF, weF, wtF, tconst);

    {
        int nt = (N_NODES + 63) / 64;
        k_proj<<<nt, 256, 0, stream>>>(node_features, b_node, wnF, node_proj, N_NODES, nt);
    }
    {
        int nt = (N_EDGES + 63) / 64;
        k_proj<<<nt, 256, 0, stream>>>(edge_features, b_edge, weF, edge_proj, N_EDGES, nt);
    }

    // layer 1: rows = B*K; nbrs gathered from node_proj; partial -> emb1 (bf16)
    k_gather<false><<<(BATCH * KNBR) / 4, 256, 0, stream>>>(
        node_proj, edge_proj, node_proj, nbrs_l2,
        timestamps, nbrs_l1, eidx_l1, etime_l1,
        b_time, time_w, time_ph, tconst,
        nullptr, emb1, csum1);
    {
        int nt = (BATCH * KNBR + 63) / 64;
        k_tgemm<false><<<nt, 256, 0, stream>>>(csum1, wtF, nullptr, emb1, BATCH * KNBR, nt);
    }

    // layer 2: rows = B; nbrs from contiguous emb1 (bf16); partial -> d_out (f32)
    k_gather<true><<<BATCH / 4, 256, 0, stream>>>(
        node_proj, edge_proj, emb1, source_nodes,
        timestamps, nbrs_l2, eidx_l2, etime_l2,
        b_time, time_w, time_ph, tconst,
        (float*)d_out, nullptr, csum2);
    {
        int nt = (BATCH + 63) / 64;
        k_tgemm<true><<<nt, 256, 0, stream>>>(csum2, wtF, (float*)d_out, nullptr, BATCH, nt);
    }
}

// Round 4
// 605.507 us; speedup vs baseline: 1.9501x; 1.3915x over previous
//
#include <hip/hip_runtime.h>
#include <hip/hip_bf16.h>
#include <stdint.h>
#include <string.h>

#define N_NODES 500000
#define N_EDGES 1000000
#define BATCH   4096
#define KNBR    20
#define DN      172
#define DT      100
#define DOUT    128

#define KSTEPS   6    // ceil(172/32)
#define KSTEPS_T 4    // ceil(100/32) padded to 128
#define NCT      8    // 128 / 16 col tiles
#define CSW      112  // csum row width (bf16), 224 B, 16B-aligned

typedef __attribute__((ext_vector_type(8))) short   bf16x8;
typedef __attribute__((ext_vector_type(4))) float   f32x4;
typedef __attribute__((ext_vector_type(2))) float   f32x2;

#define INV2PI 0.15915494309189535f

__device__ inline short f2bf(float f) {
    __hip_bfloat16 h = __float2bfloat16(f);
    short s;
    memcpy(&s, &h, 2);
    return s;
}
__device__ inline float bflo(uint32_t u) { return __uint_as_float(u << 16); }
__device__ inline float bfhi(uint32_t u) { return __uint_as_float(u & 0xffff0000u); }

// ---------------------------------------------------------------------------
// Prep (parallel): blocks 0..31 build B-fragment arrays (1 slot / thread),
// block 32 computes tconst = cos(phase) @ W_time + b_time.
// B-frag slot (ct, s, lane): col = ct*16 + (lane&15), k = s*32 + (lane>>4)*8 + j
// ---------------------------------------------------------------------------
__global__ void k_prep(const float* __restrict__ Wn, const float* __restrict__ We,
                       const float* __restrict__ Wt, const float* __restrict__ bt,
                       const float* __restrict__ tp,
                       short* __restrict__ wnF, short* __restrict__ weF,
                       short* __restrict__ wtF, float* __restrict__ tconst)
{
    const int NS6 = NCT * KSTEPS * 64;    // 3072
    const int NS4 = NCT * KSTEPS_T * 64;  // 2048
    if (blockIdx.x < 32) {
        const int idx = blockIdx.x * 256 + threadIdx.x;   // 8192 = 2*NS6+NS4
        const float* W;
        short* dst;
        int slot, ks;
        if (idx < NS6)          { W = Wn; dst = wnF; slot = idx;           ks = KSTEPS; }
        else if (idx < 2 * NS6) { W = We; dst = weF; slot = idx - NS6;     ks = KSTEPS; }
        else                    { W = Wt; dst = wtF; slot = idx - 2 * NS6; ks = KSTEPS_T; }
        const int kd = (ks == KSTEPS) ? DN : DT;
        int ct  = slot / (ks * 64);
        int rem = slot % (ks * 64);
        int s   = rem / 64;
        int l   = rem % 64;
        int col   = ct * 16 + (l & 15);
        int kbase = s * 32 + (l >> 4) * 8;
        bf16x8 sv;
        #pragma unroll
        for (int j = 0; j < 8; ++j) {
            int k = kbase + j;
            sv[j] = f2bf((k < kd) ? W[k * DOUT + col] : 0.0f);
        }
        *(bf16x8*)(dst + (size_t)slot * 8) = sv;
    } else {
        const int tid = threadIdx.x;
        if (tid < DOUT) {
            float acc = bt[tid];
            for (int j = 0; j < DT; ++j)
                acc += cosf(tp[j]) * Wt[j * DOUT + tid];
            tconst[tid] = acc;
        }
    }
}

// ---------------------------------------------------------------------------
// Projection GEMM: out[r][c] = feat[r][:DN] @ W[:,c] + bias[c], bf16 out.
// 4 waves x 16 rows = 64 rows/block. All 12 A-vector loads per tile issued
// up-front (max MLP), then cvt + MFMA. Lane l covers row (l&15),
// k = s*32+(l>>4)*8 .. +8 -> 16 rows x 128B per k-step, coalesced.
// ---------------------------------------------------------------------------
__global__ __launch_bounds__(256)
void k_proj(const float* __restrict__ feat, const float* __restrict__ bias,
            const short* __restrict__ wfrag, short* __restrict__ out,
            int nrows, int ntiles)
{
    __shared__ __attribute__((aligned(16))) short lds_b[NCT * KSTEPS * 64 * 8];  // 48 KB
    const int tid = threadIdx.x, lane = tid & 63, wv = tid >> 6;

    #pragma unroll
    for (int i = 0; i < 12; ++i)
        ((f32x4*)lds_b)[tid + i * 256] = ((const f32x4*)wfrag)[tid + i * 256];
    __syncthreads();

    const int r15 = lane & 15, kq = lane >> 4, c0 = lane & 15;
    float bs[NCT];
    #pragma unroll
    for (int ct = 0; ct < NCT; ++ct) bs[ct] = bias[ct * 16 + c0];

    for (int tile = blockIdx.x; tile < ntiles; tile += gridDim.x) {
        const int row0 = tile * 64 + wv * 16;
        int r = row0 + r15;
        if (r > nrows - 1) r = nrows - 1;
        const float* fp = feat + (size_t)r * DN;

        // issue ALL A loads for this tile before any use
        f32x4 av[2 * KSTEPS];
        #pragma unroll
        for (int s = 0; s < KSTEPS; ++s) {
            const int k0 = s * 32 + kq * 8;
            av[2 * s]     = (f32x4){0, 0, 0, 0};
            av[2 * s + 1] = (f32x4){0, 0, 0, 0};
            if (k0 + 4 <= DN) av[2 * s]     = *(const f32x4*)(fp + k0);
            if (k0 + 8 <= DN) av[2 * s + 1] = *(const f32x4*)(fp + k0 + 4);
        }

        f32x4 acc[NCT];
        #pragma unroll
        for (int ct = 0; ct < NCT; ++ct) acc[ct] = (f32x4){0, 0, 0, 0};

        #pragma unroll
        for (int s = 0; s < KSTEPS; ++s) {
            bf16x8 a;
            #pragma unroll
            for (int j = 0; j < 4; ++j) a[j] = f2bf(av[2 * s][j]);
            #pragma unroll
            for (int j = 0; j < 4; ++j) a[4 + j] = f2bf(av[2 * s + 1][j]);
            #pragma unroll
            for (int ct = 0; ct < NCT; ++ct) {
                bf16x8 b = *(const bf16x8*)&lds_b[((ct * KSTEPS + s) * 64 + lane) * 8];
                acc[ct] = __builtin_amdgcn_mfma_f32_16x16x32_bf16(a, b, acc[ct], 0, 0, 0);
            }
        }
        const int rbase = row0 + (lane >> 4) * 4;
        #pragma unroll
        for (int ct = 0; ct < NCT; ++ct) {
            const int c = ct * 16 + c0;
            #pragma unroll
            for (int rr = 0; rr < 4; ++rr) {
                int grow = rbase + rr;
                if (grow < nrows)
                    out[(size_t)grow * DOUT + c] = f2bf(acc[ct][rr] + bs[ct]);
            }
        }
    }
}

// ---------------------------------------------------------------------------
// Gather layer (no LDS). One wave per output row. All gather loads issued
// unconditionally up-front (max MLP); validity handled by fma(w, ., .).
// Writes: partial = src + tconst + (msg_sum + cnt*b_time)/cnt   (bf16 or f32)
//         csum'   = (sum_valid cos_vec) / cnt  as bf16, CSW-wide, zero-padded.
// Time matvec deferred to k_tgemm.
// ---------------------------------------------------------------------------
template <bool L2>
__global__ __launch_bounds__(256)
void k_gather(const short* __restrict__ node_proj, const short* __restrict__ edge_proj,
              const short* __restrict__ nbr_tab,
              const int* __restrict__ src_idx, const float* __restrict__ ts_arr,
              const int* __restrict__ nbrs, const int* __restrict__ eidx,
              const float* __restrict__ etime,
              const float* __restrict__ bt, const float* __restrict__ tw,
              const float* __restrict__ tp, const float* __restrict__ tconst,
              float* __restrict__ partial_f32, short* __restrict__ partial_bf16,
              short* __restrict__ csum_out)
{
    const int tid = threadIdx.x, lane = tid & 63, wv = tid >> 6;
    const int row = blockIdx.x * 4 + wv;

    int nb = 0, ei = 0;
    float et = 0.0f;
    if (lane < KNBR) {
        nb = nbrs[(size_t)row * KNBR + lane];
        ei = eidx[(size_t)row * KNBR + lane];
        et = etime[(size_t)row * KNBR + lane];
    }
    const unsigned long long vm = __ballot(lane < KNBR && nb != 0);
    const int   cnt = __popcll(vm);
    const float ts  = L2 ? ts_arr[row] : ts_arr[row / KNBR];

    int   ek[KNBR], nk[KNBR];
    float dk[KNBR];
    #pragma unroll
    for (int k = 0; k < KNBR; ++k) ek[k] = __shfl(ei, k);
    #pragma unroll
    for (int k = 0; k < KNBR; ++k) dk[k] = ts - __shfl(et, k);
    if (!L2) {
        #pragma unroll
        for (int k = 0; k < KNBR; ++k) nk[k] = __shfl(nb, k);
    }

    const int d2 = lane * 2;
    // issue every global load before any compute
    const int si = src_idx[row];
    uint32_t ev[KNBR], nv[KNBR];
    #pragma unroll
    for (int k = 0; k < KNBR; ++k)
        ev[k] = *(const uint32_t*)(edge_proj + (size_t)ek[k] * DOUT + d2);
    #pragma unroll
    for (int k = 0; k < KNBR; ++k) {
        size_t ri = L2 ? ((size_t)row * KNBR + k) : (size_t)nk[k];
        nv[k] = *(const uint32_t*)(nbr_tab + ri * DOUT + d2);
    }
    const uint32_t sv  = *(const uint32_t*)(node_proj + (size_t)si * DOUT + d2);
    const f32x2    bt2 = *(const f32x2*)&bt[d2];
    const f32x2    tc2 = *(const f32x2*)&tconst[d2];

    const float wr0 = tw[lane] * INV2PI;
    const float pr0 = tp[lane] * INV2PI;
    float wr1 = 0.0f, pr1 = 0.0f;
    if (lane < DT - 64) { wr1 = tw[64 + lane] * INV2PI; pr1 = tp[64 + lane] * INV2PI; }

    float cs0 = 0, cs1 = 0, ms0 = 0, ms1 = 0;
    #pragma unroll
    for (int k = 0; k < KNBR; ++k) {
        const float w = (float)(int)((vm >> k) & 1ull);
        float r0 = dk[k] * wr0 + pr0; r0 -= floorf(r0);
        float r1 = dk[k] * wr1 + pr1; r1 -= floorf(r1);
        cs0 = fmaf(w, __builtin_amdgcn_cosf(r0), cs0);
        cs1 = fmaf(w, __builtin_amdgcn_cosf(r1), cs1);
        ms0 = fmaf(w, bflo(ev[k]) + bflo(nv[k]), ms0);
        ms1 = fmaf(w, bfhi(ev[k]) + bfhi(nv[k]), ms1);
    }

    const float fc  = (float)cnt;
    const float inv = (cnt > 0) ? 1.0f / fc : 1.0f;

    csum_out[(size_t)row * CSW + lane] = f2bf(cs0 * inv);
    if (lane < 48)
        csum_out[(size_t)row * CSW + 64 + lane] = f2bf(lane < DT - 64 ? cs1 * inv : 0.0f);

    const float o0 = bflo(sv) + tc2[0] + (ms0 + fc * bt2[0]) * inv;
    const float o1 = bfhi(sv) + tc2[1] + (ms1 + fc * bt2[1]) * inv;
    if (L2) {
        *(f32x2*)(partial_f32 + (size_t)row * DOUT + d2) = (f32x2){o0, o1};
    } else {
        uint32_t u = (uint32_t)(uint16_t)f2bf(o0) | ((uint32_t)(uint16_t)f2bf(o1) << 16);
        *(uint32_t*)(partial_bf16 + (size_t)row * DOUT + d2) = u;
    }
}

// ---------------------------------------------------------------------------
// Time GEMM: io[row][c] += csum'[row][:] @ W_time[:,c]   (in-place RMW).
// csum' is bf16, CSW-wide, zero-padded -> A-frags direct-loaded, no bounds.
// ---------------------------------------------------------------------------
template <bool F32IO>
__global__ __launch_bounds__(256)
void k_tgemm(const short* __restrict__ csum, const short* __restrict__ wtF,
             float* __restrict__ io_f32, short* __restrict__ io_bf16,
             int nrows, int ntiles)
{
    __shared__ __attribute__((aligned(16))) short lds_b[NCT * KSTEPS_T * 64 * 8];  // 32 KB
    const int tid = threadIdx.x, lane = tid & 63, wv = tid >> 6;

    #pragma unroll
    for (int i = 0; i < 8; ++i)
        ((f32x4*)lds_b)[tid + i * 256] = ((const f32x4*)wtF)[tid + i * 256];
    __syncthreads();

    const int r15 = lane & 15, kq = lane >> 4, c0 = lane & 15;

    for (int tile = blockIdx.x; tile < ntiles; tile += gridDim.x) {
        const int row0 = tile * 64 + wv * 16;
        int r = row0 + r15;
        if (r > nrows - 1) r = nrows - 1;
        const short* ap = csum + (size_t)r * CSW;

        f32x4 acc[NCT];
        #pragma unroll
        for (int ct = 0; ct < NCT; ++ct) acc[ct] = (f32x4){0, 0, 0, 0};

        #pragma unroll
        for (int s = 0; s < KSTEPS_T; ++s) {
            const int k0 = s * 32 + kq * 8;
            bf16x8 a = (bf16x8)(short)0;
            if (k0 + 8 <= CSW) a = *(const bf16x8*)(ap + k0);
            #pragma unroll
            for (int ct = 0; ct < NCT; ++ct) {
                bf16x8 b = *(const bf16x8*)&lds_b[((ct * KSTEPS_T + s) * 64 + lane) * 8];
                acc[ct] = __builtin_amdgcn_mfma_f32_16x16x32_bf16(a, b, acc[ct], 0, 0, 0);
            }
        }
        const int rbase = row0 + (lane >> 4) * 4;
        #pragma unroll
        for (int ct = 0; ct < NCT; ++ct) {
            const int c = ct * 16 + c0;
            #pragma unroll
            for (int rr = 0; rr < 4; ++rr) {
                int grow = rbase + rr;
                if (grow < nrows) {
                    size_t off = (size_t)grow * DOUT + c;
                    if (F32IO) {
                        io_f32[off] += acc[ct][rr];
                    } else {
                        float oldv = bflo((uint32_t)(uint16_t)io_bf16[off]);
                        io_bf16[off] = f2bf(oldv + acc[ct][rr]);
                    }
                }
            }
        }
    }
}

// ---------------------------------------------------------------------------
extern "C" void kernel_launch(void* const* d_in, const int* in_sizes, int n_in,
                              void* d_out, int out_size, void* d_ws, size_t ws_size,
                              hipStream_t stream)
{
    const float* node_features = (const float*)d_in[0];
    const float* edge_features = (const float*)d_in[1];
    const float* W_node  = (const float*)d_in[2];
    const float* b_node  = (const float*)d_in[3];
    const float* W_time  = (const float*)d_in[4];
    const float* b_time  = (const float*)d_in[5];
    const float* W_edge  = (const float*)d_in[6];
    const float* b_edge  = (const float*)d_in[7];
    const float* time_w  = (const float*)d_in[8];
    const float* time_ph = (const float*)d_in[9];
    const int*   source_nodes = (const int*)d_in[10];
    const float* timestamps   = (const float*)d_in[11];
    const int*   nbrs_l2  = (const int*)d_in[12];
    const int*   eidx_l2  = (const int*)d_in[13];
    const float* etime_l2 = (const float*)d_in[14];
    const int*   nbrs_l1  = (const int*)d_in[15];
    const int*   eidx_l1  = (const int*)d_in[16];
    const float* etime_l1 = (const float*)d_in[17];

    // workspace layout (all offsets 256B-aligned)
    char*  ws        = (char*)d_ws;
    short* node_proj = (short*)(ws);                    // 128,000,000
    short* edge_proj = (short*)(ws + 128000000);        // 256,000,000
    short* emb1      = (short*)(ws + 384000000);        //  20,971,520 (bf16)
    short* csum1     = (short*)(ws + 404971520);        //  18,350,080
    short* csum2     = (short*)(ws + 423321600);        //     917,504
    float* tconst    = (float*)(ws + 424239104);        //         512
    short* wnF       = (short*)(ws + 424239616);        //      49,152
    short* weF       = (short*)(ws + 424288768);        //      49,152
    short* wtF       = (short*)(ws + 424337920);        //      32,768 -> 424,370,688
    if (ws_size < 424400000ull) return;

    k_prep<<<33, 256, 0, stream>>>(W_node, W_edge, W_time, b_time, time_ph,
                                   wnF, weF, wtF, tconst);

    {
        int nt = (N_NODES + 63) / 64;
        k_proj<<<nt, 256, 0, stream>>>(node_features, b_node, wnF, node_proj, N_NODES, nt);
    }
    {
        int nt = (N_EDGES + 63) / 64;
        k_proj<<<nt, 256, 0, stream>>>(edge_features, b_edge, weF, edge_proj, N_EDGES, nt);
    }

    // layer 1: rows = B*K; nbrs gathered from node_proj; partial -> emb1 (bf16)
    k_gather<false><<<(BATCH * KNBR) / 4, 256, 0, stream>>>(
        node_proj, edge_proj, node_proj, nbrs_l2,
        timestamps, nbrs_l1, eidx_l1, etime_l1,
        b_time, time_w, time_ph, tconst,
        nullptr, emb1, csum1);
    {
        int nt = (BATCH * KNBR + 63) / 64;
        k_tgemm<false><<<nt, 256, 0, stream>>>(csum1, wtF, nullptr, emb1, BATCH * KNBR, nt);
    }

    // layer 2: rows = B; nbrs from contiguous emb1 (bf16); partial -> d_out (f32)
    k_gather<true><<<BATCH / 4, 256, 0, stream>>>(
        node_proj, edge_proj, emb1, source_nodes,
        timestamps, nbrs_l2, eidx_l2, etime_l2,
        b_time, time_w, time_ph, tconst,
        (float*)d_out, nullptr, csum2);
    {
        int nt = (BATCH + 63) / 64;
        k_tgemm<true><<<nt, 256, 0, stream>>>(csum2, wtF, (float*)d_out, nullptr, BATCH, nt);
    }
}

// Round 5
// 558.989 us; speedup vs baseline: 2.1124x; 1.0832x over previous
//
#include <hip/hip_runtime.h>
#include <hip/hip_bf16.h>
#include <stdint.h>
#include <string.h>

#define N_NODES 500000
#define N_EDGES 1000000
#define BATCH   4096
#define KNBR    20
#define DN      172
#define DT      100
#define DOUT    128

#define KSTEPS   6    // ceil(172/32)
#define KSTEPS_T 4    // ceil(100/32) padded to 128
#define NCT      8    // 128 / 16 col tiles
#define CSW      112  // csum row width (bf16), 224 B, 16B-aligned

#define NMARK   (BATCH * KNBR * KNBR + BATCH * KNBR)   // 1,720,320 edge refs

typedef __attribute__((ext_vector_type(8))) short   bf16x8;
typedef __attribute__((ext_vector_type(4))) float   f32x4;
typedef __attribute__((ext_vector_type(2))) float   f32x2;

#define INV2PI 0.15915494309189535f

__device__ inline short f2bf(float f) {
    __hip_bfloat16 h = __float2bfloat16(f);
    short s;
    memcpy(&s, &h, 2);
    return s;
}
__device__ inline float bflo(uint32_t u) { return __uint_as_float(u << 16); }
__device__ inline float bfhi(uint32_t u) { return __uint_as_float(u & 0xffff0000u); }

// ---------------------------------------------------------------------------
__global__ void k_zero(uint32_t* __restrict__ p, int ndw)
{
    for (int i = blockIdx.x * blockDim.x + threadIdx.x; i < ndw;
         i += gridDim.x * blockDim.x)
        p[i] = 0;
}

__global__ void k_mark(const int* __restrict__ e1, const int* __restrict__ e2,
                       unsigned char* __restrict__ emap)
{
    const int n1 = BATCH * KNBR * KNBR;
    for (int i = blockIdx.x * blockDim.x + threadIdx.x; i < NMARK;
         i += gridDim.x * blockDim.x) {
        int e = (i < n1) ? e1[i] : e2[i - n1];
        emap[e] = 1;
    }
}

// ---------------------------------------------------------------------------
// Prep (parallel): blocks 0..31 build B-fragment arrays (1 slot / thread),
// block 32 computes tconst = cos(phase) @ W_time + b_time.
// B-frag slot (ct, s, lane): col = ct*16 + (lane&15), k = s*32 + (lane>>4)*8 + j
// ---------------------------------------------------------------------------
__global__ void k_prep(const float* __restrict__ Wn, const float* __restrict__ We,
                       const float* __restrict__ Wt, const float* __restrict__ bt,
                       const float* __restrict__ tp,
                       short* __restrict__ wnF, short* __restrict__ weF,
                       short* __restrict__ wtF, float* __restrict__ tconst)
{
    const int NS6 = NCT * KSTEPS * 64;    // 3072
    const int NS4 = NCT * KSTEPS_T * 64;  // 2048
    if (blockIdx.x < 32) {
        const int idx = blockIdx.x * 256 + threadIdx.x;   // 8192 = 2*NS6+NS4
        const float* W;
        short* dst;
        int slot, ks;
        if (idx < NS6)          { W = Wn; dst = wnF; slot = idx;           ks = KSTEPS; }
        else if (idx < 2 * NS6) { W = We; dst = weF; slot = idx - NS6;     ks = KSTEPS; }
        else                    { W = Wt; dst = wtF; slot = idx - 2 * NS6; ks = KSTEPS_T; }
        const int kd = (ks == KSTEPS) ? DN : DT;
        int ct  = slot / (ks * 64);
        int rem = slot % (ks * 64);
        int s   = rem / 64;
        int l   = rem % 64;
        int col   = ct * 16 + (l & 15);
        int kbase = s * 32 + (l >> 4) * 8;
        bf16x8 sv;
        #pragma unroll
        for (int j = 0; j < 8; ++j) {
            int k = kbase + j;
            sv[j] = f2bf((k < kd) ? W[k * DOUT + col] : 0.0f);
        }
        *(bf16x8*)(dst + (size_t)slot * 8) = sv;
    } else {
        const int tid = threadIdx.x;
        if (tid < DOUT) {
            float acc = bt[tid];
            for (int j = 0; j < DT; ++j)
                acc += cosf(tp[j]) * Wt[j * DOUT + tid];
            tconst[tid] = acc;
        }
    }
}

// ---------------------------------------------------------------------------
// Projection GEMM, persistent + software-pipelined.
// out[r][c] = feat[r][:DN] @ W[:,c] + bias[c], bf16 out.
// 4 waves x 16 rows = 64 rows/tile; block loops tiles with stride gridDim.x,
// double-buffering the 12 A-vector loads in registers so tile t+1's HBM reads
// overlap tile t's MFMA+store. rowmap != nullptr skips dead rows (load+store).
// ---------------------------------------------------------------------------
#define ALOAD(AV, TILE)                                                        \
    {                                                                          \
        const int row0_ = (TILE) * 64 + wv * 16;                               \
        int r_ = row0_ + r15;                                                  \
        if (r_ > nrows - 1) r_ = nrows - 1;                                    \
        const bool live_ = (rowmap == nullptr) || (rowmap[r_] != 0);           \
        const float* fp_ = feat + (size_t)r_ * DN;                             \
        _Pragma("unroll")                                                      \
        for (int s_ = 0; s_ < KSTEPS; ++s_) {                                  \
            const int k0_ = s_ * 32 + kq * 8;                                  \
            AV[2 * s_]     = (f32x4){0, 0, 0, 0};                              \
            AV[2 * s_ + 1] = (f32x4){0, 0, 0, 0};                              \
            if (live_) {                                                       \
                if (k0_ + 4 <= DN) AV[2 * s_]     = *(const f32x4*)(fp_ + k0_);\
                if (k0_ + 8 <= DN) AV[2 * s_ + 1] = *(const f32x4*)(fp_ + k0_ + 4); \
            }                                                                  \
        }                                                                      \
    }

#define CSTORE(AV, TILE)                                                       \
    {                                                                          \
        f32x4 acc_[NCT];                                                       \
        _Pragma("unroll")                                                      \
        for (int ct_ = 0; ct_ < NCT; ++ct_) acc_[ct_] = (f32x4){0, 0, 0, 0};   \
        _Pragma("unroll")                                                      \
        for (int s_ = 0; s_ < KSTEPS; ++s_) {                                  \
            bf16x8 a_;                                                         \
            _Pragma("unroll")                                                  \
            for (int j_ = 0; j_ < 4; ++j_) a_[j_]     = f2bf(AV[2 * s_][j_]);  \
            _Pragma("unroll")                                                  \
            for (int j_ = 0; j_ < 4; ++j_) a_[4 + j_] = f2bf(AV[2 * s_ + 1][j_]); \
            _Pragma("unroll")                                                  \
            for (int ct_ = 0; ct_ < NCT; ++ct_) {                              \
                bf16x8 b_ = *(const bf16x8*)&lds_b[((ct_ * KSTEPS + s_) * 64 + lane) * 8]; \
                acc_[ct_] = __builtin_amdgcn_mfma_f32_16x16x32_bf16(a_, b_, acc_[ct_], 0, 0, 0); \
            }                                                                  \
        }                                                                      \
        const int rbase_ = (TILE) * 64 + wv * 16 + (lane >> 4) * 4;            \
        _Pragma("unroll")                                                      \
        for (int rr_ = 0; rr_ < 4; ++rr_) {                                    \
            const int grow_ = rbase_ + rr_;                                    \
            if (grow_ < nrows && ((rowmap == nullptr) || rowmap[grow_])) {     \
                _Pragma("unroll")                                              \
                for (int ct_ = 0; ct_ < NCT; ++ct_)                            \
                    out[(size_t)grow_ * DOUT + ct_ * 16 + c0] =                \
                        f2bf(acc_[ct_][rr_] + bs[ct_]);                        \
            }                                                                  \
        }                                                                      \
    }

__global__ __launch_bounds__(256)
void k_proj(const float* __restrict__ feat, const float* __restrict__ bias,
            const short* __restrict__ wfrag, const unsigned char* __restrict__ rowmap,
            short* __restrict__ out, int nrows, int ntiles)
{
    __shared__ __attribute__((aligned(16))) short lds_b[NCT * KSTEPS * 64 * 8];  // 48 KB
    const int tid = threadIdx.x, lane = tid & 63, wv = tid >> 6;

    #pragma unroll
    for (int i = 0; i < 12; ++i)
        ((f32x4*)lds_b)[tid + i * 256] = ((const f32x4*)wfrag)[tid + i * 256];
    __syncthreads();

    const int r15 = lane & 15, kq = lane >> 4, c0 = lane & 15;
    float bs[NCT];
    #pragma unroll
    for (int ct = 0; ct < NCT; ++ct) bs[ct] = bias[ct * 16 + c0];

    int t = blockIdx.x;
    if (t >= ntiles) return;

    f32x4 avA[2 * KSTEPS], avB[2 * KSTEPS];
    ALOAD(avA, t);
    for (;;) {
        int tn = t + gridDim.x;
        if (tn < ntiles) ALOAD(avB, tn);
        CSTORE(avA, t);
        if (tn >= ntiles) break;
        t = tn;
        tn = t + gridDim.x;
        if (tn < ntiles) ALOAD(avA, tn);
        CSTORE(avB, t);
        if (tn >= ntiles) break;
        t = tn;
    }
}

// ---------------------------------------------------------------------------
// Gather layer (no LDS). One wave per output row. All gather loads issued
// unconditionally up-front (max MLP); validity handled by fma(w, ., .).
// Writes: partial = src + tconst + (msg_sum + cnt*b_time)/cnt   (bf16 or f32)
//         csum'   = (sum_valid cos_vec) / cnt  as bf16, CSW-wide, zero-padded.
// Time matvec deferred to k_tgemm.
// ---------------------------------------------------------------------------
template <bool L2>
__global__ __launch_bounds__(256)
void k_gather(const short* __restrict__ node_proj, const short* __restrict__ edge_proj,
              const short* __restrict__ nbr_tab,
              const int* __restrict__ src_idx, const float* __restrict__ ts_arr,
              const int* __restrict__ nbrs, const int* __restrict__ eidx,
              const float* __restrict__ etime,
              const float* __restrict__ bt, const float* __restrict__ tw,
              const float* __restrict__ tp, const float* __restrict__ tconst,
              float* __restrict__ partial_f32, short* __restrict__ partial_bf16,
              short* __restrict__ csum_out)
{
    const int tid = threadIdx.x, lane = tid & 63, wv = tid >> 6;
    const int row = blockIdx.x * 4 + wv;

    int nb = 0, ei = 0;
    float et = 0.0f;
    if (lane < KNBR) {
        nb = nbrs[(size_t)row * KNBR + lane];
        ei = eidx[(size_t)row * KNBR + lane];
        et = etime[(size_t)row * KNBR + lane];
    }
    const unsigned long long vm = __ballot(lane < KNBR && nb != 0);
    const int   cnt = __popcll(vm);
    const float ts  = L2 ? ts_arr[row] : ts_arr[row / KNBR];

    int   ek[KNBR], nk[KNBR];
    float dk[KNBR];
    #pragma unroll
    for (int k = 0; k < KNBR; ++k) ek[k] = __shfl(ei, k);
    #pragma unroll
    for (int k = 0; k < KNBR; ++k) dk[k] = ts - __shfl(et, k);
    if (!L2) {
        #pragma unroll
        for (int k = 0; k < KNBR; ++k) nk[k] = __shfl(nb, k);
    }

    const int d2 = lane * 2;
    // issue every global load before any compute
    const int si = src_idx[row];
    uint32_t ev[KNBR], nv[KNBR];
    #pragma unroll
    for (int k = 0; k < KNBR; ++k)
        ev[k] = *(const uint32_t*)(edge_proj + (size_t)ek[k] * DOUT + d2);
    #pragma unroll
    for (int k = 0; k < KNBR; ++k) {
        size_t ri = L2 ? ((size_t)row * KNBR + k) : (size_t)nk[k];
        nv[k] = *(const uint32_t*)(nbr_tab + ri * DOUT + d2);
    }
    const uint32_t sv  = *(const uint32_t*)(node_proj + (size_t)si * DOUT + d2);
    const f32x2    bt2 = *(const f32x2*)&bt[d2];
    const f32x2    tc2 = *(const f32x2*)&tconst[d2];

    const float wr0 = tw[lane] * INV2PI;
    const float pr0 = tp[lane] * INV2PI;
    float wr1 = 0.0f, pr1 = 0.0f;
    if (lane < DT - 64) { wr1 = tw[64 + lane] * INV2PI; pr1 = tp[64 + lane] * INV2PI; }

    float cs0 = 0, cs1 = 0, ms0 = 0, ms1 = 0;
    #pragma unroll
    for (int k = 0; k < KNBR; ++k) {
        const float w = (float)(int)((vm >> k) & 1ull);
        float r0 = dk[k] * wr0 + pr0; r0 -= floorf(r0);
        float r1 = dk[k] * wr1 + pr1; r1 -= floorf(r1);
        cs0 = fmaf(w, __builtin_amdgcn_cosf(r0), cs0);
        cs1 = fmaf(w, __builtin_amdgcn_cosf(r1), cs1);
        ms0 = fmaf(w, bflo(ev[k]) + bflo(nv[k]), ms0);
        ms1 = fmaf(w, bfhi(ev[k]) + bfhi(nv[k]), ms1);
    }

    const float fc  = (float)cnt;
    const float inv = (cnt > 0) ? 1.0f / fc : 1.0f;

    csum_out[(size_t)row * CSW + lane] = f2bf(cs0 * inv);
    if (lane < 48)
        csum_out[(size_t)row * CSW + 64 + lane] = f2bf(lane < DT - 64 ? cs1 * inv : 0.0f);

    const float o0 = bflo(sv) + tc2[0] + (ms0 + fc * bt2[0]) * inv;
    const float o1 = bfhi(sv) + tc2[1] + (ms1 + fc * bt2[1]) * inv;
    if (L2) {
        *(f32x2*)(partial_f32 + (size_t)row * DOUT + d2) = (f32x2){o0, o1};
    } else {
        uint32_t u = (uint32_t)(uint16_t)f2bf(o0) | ((uint32_t)(uint16_t)f2bf(o1) << 16);
        *(uint32_t*)(partial_bf16 + (size_t)row * DOUT + d2) = u;
    }
}

// ---------------------------------------------------------------------------
// Time GEMM: io[row][c] += csum'[row][:] @ W_time[:,c]   (in-place RMW).
// csum' is bf16, CSW-wide, zero-padded -> A-frags direct-loaded, no bounds.
// ---------------------------------------------------------------------------
template <bool F32IO>
__global__ __launch_bounds__(256)
void k_tgemm(const short* __restrict__ csum, const short* __restrict__ wtF,
             float* __restrict__ io_f32, short* __restrict__ io_bf16,
             int nrows, int ntiles)
{
    __shared__ __attribute__((aligned(16))) short lds_b[NCT * KSTEPS_T * 64 * 8];  // 32 KB
    const int tid = threadIdx.x, lane = tid & 63, wv = tid >> 6;

    #pragma unroll
    for (int i = 0; i < 8; ++i)
        ((f32x4*)lds_b)[tid + i * 256] = ((const f32x4*)wtF)[tid + i * 256];
    __syncthreads();

    const int r15 = lane & 15, kq = lane >> 4, c0 = lane & 15;

    for (int tile = blockIdx.x; tile < ntiles; tile += gridDim.x) {
        const int row0 = tile * 64 + wv * 16;
        int r = row0 + r15;
        if (r > nrows - 1) r = nrows - 1;
        const short* ap = csum + (size_t)r * CSW;

        f32x4 acc[NCT];
        #pragma unroll
        for (int ct = 0; ct < NCT; ++ct) acc[ct] = (f32x4){0, 0, 0, 0};

        #pragma unroll
        for (int s = 0; s < KSTEPS_T; ++s) {
            const int k0 = s * 32 + kq * 8;
            bf16x8 a = (bf16x8)(short)0;
            if (k0 + 8 <= CSW) a = *(const bf16x8*)(ap + k0);
            #pragma unroll
            for (int ct = 0; ct < NCT; ++ct) {
                bf16x8 b = *(const bf16x8*)&lds_b[((ct * KSTEPS_T + s) * 64 + lane) * 8];
                acc[ct] = __builtin_amdgcn_mfma_f32_16x16x32_bf16(a, b, acc[ct], 0, 0, 0);
            }
        }
        const int rbase = row0 + (lane >> 4) * 4;
        #pragma unroll
        for (int ct = 0; ct < NCT; ++ct) {
            const int c = ct * 16 + c0;
            #pragma unroll
            for (int rr = 0; rr < 4; ++rr) {
                int grow = rbase + rr;
                if (grow < nrows) {
                    size_t off = (size_t)grow * DOUT + c;
                    if (F32IO) {
                        io_f32[off] += acc[ct][rr];
                    } else {
                        float oldv = bflo((uint32_t)(uint16_t)io_bf16[off]);
                        io_bf16[off] = f2bf(oldv + acc[ct][rr]);
                    }
                }
            }
        }
    }
}

// ---------------------------------------------------------------------------
extern "C" void kernel_launch(void* const* d_in, const int* in_sizes, int n_in,
                              void* d_out, int out_size, void* d_ws, size_t ws_size,
                              hipStream_t stream)
{
    const float* node_features = (const float*)d_in[0];
    const float* edge_features = (const float*)d_in[1];
    const float* W_node  = (const float*)d_in[2];
    const float* b_node  = (const float*)d_in[3];
    const float* W_time  = (const float*)d_in[4];
    const float* b_time  = (const float*)d_in[5];
    const float* W_edge  = (const float*)d_in[6];
    const float* b_edge  = (const float*)d_in[7];
    const float* time_w  = (const float*)d_in[8];
    const float* time_ph = (const float*)d_in[9];
    const int*   source_nodes = (const int*)d_in[10];
    const float* timestamps   = (const float*)d_in[11];
    const int*   nbrs_l2  = (const int*)d_in[12];
    const int*   eidx_l2  = (const int*)d_in[13];
    const float* etime_l2 = (const float*)d_in[14];
    const int*   nbrs_l1  = (const int*)d_in[15];
    const int*   eidx_l1  = (const int*)d_in[16];
    const float* etime_l1 = (const float*)d_in[17];

    // workspace layout (all offsets 256B-aligned)
    char*  ws        = (char*)d_ws;
    short* node_proj = (short*)(ws);                    // 128,000,000
    short* edge_proj = (short*)(ws + 128000000);        // 256,000,000
    short* emb1      = (short*)(ws + 384000000);        //  20,971,520 (bf16)
    short* csum1     = (short*)(ws + 404971520);        //  18,350,080
    short* csum2     = (short*)(ws + 423321600);        //     917,504
    float* tconst    = (float*)(ws + 424239104);        //         512
    short* wnF       = (short*)(ws + 424239616);        //      49,152
    short* weF       = (short*)(ws + 424288768);        //      49,152
    short* wtF       = (short*)(ws + 424337920);        //      32,768
    unsigned char* emap = (unsigned char*)(ws + 424371200); // 1,000,000 -> 425,371,200
    if (ws_size < 425500000ull) return;

    k_zero<<<128, 256, 0, stream>>>((uint32_t*)emap, N_EDGES / 4);
    k_mark<<<512, 256, 0, stream>>>(eidx_l1, eidx_l2, emap);
    k_prep<<<33, 256, 0, stream>>>(W_node, W_edge, W_time, b_time, time_ph,
                                   wnF, weF, wtF, tconst);

    {
        int nt = (N_NODES + 63) / 64;
        k_proj<<<1024, 256, 0, stream>>>(node_features, b_node, wnF, nullptr,
                                         node_proj, N_NODES, nt);
    }
    {
        int nt = (N_EDGES + 63) / 64;
        k_proj<<<1024, 256, 0, stream>>>(edge_features, b_edge, weF, emap,
                                         edge_proj, N_EDGES, nt);
    }

    // layer 1: rows = B*K; nbrs gathered from node_proj; partial -> emb1 (bf16)
    k_gather<false><<<(BATCH * KNBR) / 4, 256, 0, stream>>>(
        node_proj, edge_proj, node_proj, nbrs_l2,
        timestamps, nbrs_l1, eidx_l1, etime_l1,
        b_time, time_w, time_ph, tconst,
        nullptr, emb1, csum1);
    {
        int nt = (BATCH * KNBR + 63) / 64;
        k_tgemm<false><<<nt, 256, 0, stream>>>(csum1, wtF, nullptr, emb1, BATCH * KNBR, nt);
    }

    // layer 2: rows = B; nbrs from contiguous emb1 (bf16); partial -> d_out (f32)
    k_gather<true><<<BATCH / 4, 256, 0, stream>>>(
        node_proj, edge_proj, emb1, source_nodes,
        timestamps, nbrs_l2, eidx_l2, etime_l2,
        b_time, time_w, time_ph, tconst,
        (float*)d_out, nullptr, csum2);
    {
        int nt = (BATCH + 63) / 64;
        k_tgemm<true><<<nt, 256, 0, stream>>>(csum2, wtF, (float*)d_out, nullptr, BATCH, nt);
    }
}

// Round 6
// 554.681 us; speedup vs baseline: 2.1288x; 1.0078x over previous
//
#include <hip/hip_runtime.h>
#include <hip/hip_bf16.h>
#include <stdint.h>
#include <string.h>

#define N_NODES 500000
#define N_EDGES 1000000
#define BATCH   4096
#define KNBR    20
#define DN      172
#define DT      100
#define DOUT    128

#define KSTEPS   6    // ceil(172/32)
#define KSTEPS_T 4    // ceil(100/32) padded to 128
#define NCT      8    // 128 / 16 col tiles
#define CSW      112  // csum row width (bf16), 224 B, 16B-aligned

#define NMARK   (BATCH * KNBR * KNBR + BATCH * KNBR)   // 1,720,320 edge refs

#define NBLK_N  768
#define NBLK_E  1280

typedef __attribute__((ext_vector_type(8))) short   bf16x8;
typedef __attribute__((ext_vector_type(4))) float   f32x4;
typedef __attribute__((ext_vector_type(2))) float   f32x2;

#define INV2PI 0.15915494309189535f

__device__ inline short f2bf(float f) {
    __hip_bfloat16 h = __float2bfloat16(f);
    short s;
    memcpy(&s, &h, 2);
    return s;
}
__device__ inline float bflo(uint32_t u) { return __uint_as_float(u << 16); }
__device__ inline float bfhi(uint32_t u) { return __uint_as_float(u & 0xffff0000u); }
__device__ inline float rfl_f(float x) {
    return __uint_as_float(__builtin_amdgcn_readfirstlane(__float_as_uint(x)));
}

// ---------------------------------------------------------------------------
__global__ void k_zero(uint32_t* __restrict__ p, int ndw)
{
    for (int i = blockIdx.x * blockDim.x + threadIdx.x; i < ndw;
         i += gridDim.x * blockDim.x)
        p[i] = 0;
}

__global__ void k_mark(const int* __restrict__ e1, const int* __restrict__ e2,
                       unsigned char* __restrict__ emap)
{
    const int n1 = BATCH * KNBR * KNBR;
    for (int i = blockIdx.x * blockDim.x + threadIdx.x; i < NMARK;
         i += gridDim.x * blockDim.x) {
        int e = (i < n1) ? e1[i] : e2[i - n1];
        emap[e] = 1;
    }
}

// ---------------------------------------------------------------------------
// Prep: blocks 0..31 build B-fragment arrays, block 32 computes tconst.
// B-frag slot (ct, s, lane): col = ct*16 + (lane&15), k = s*32 + (lane>>4)*8 + j
// ---------------------------------------------------------------------------
__global__ void k_prep(const float* __restrict__ Wn, const float* __restrict__ We,
                       const float* __restrict__ Wt, const float* __restrict__ bt,
                       const float* __restrict__ tp,
                       short* __restrict__ wnF, short* __restrict__ weF,
                       short* __restrict__ wtF, float* __restrict__ tconst)
{
    const int NS6 = NCT * KSTEPS * 64;    // 3072
    const int NS4 = NCT * KSTEPS_T * 64;  // 2048
    if (blockIdx.x < 32) {
        const int idx = blockIdx.x * 256 + threadIdx.x;   // 8192 = 2*NS6+NS4
        const float* W;
        short* dst;
        int slot, ks;
        if (idx < NS6)          { W = Wn; dst = wnF; slot = idx;           ks = KSTEPS; }
        else if (idx < 2 * NS6) { W = We; dst = weF; slot = idx - NS6;     ks = KSTEPS; }
        else                    { W = Wt; dst = wtF; slot = idx - 2 * NS6; ks = KSTEPS_T; }
        const int kd = (ks == KSTEPS) ? DN : DT;
        int ct  = slot / (ks * 64);
        int rem = slot % (ks * 64);
        int s   = rem / 64;
        int l   = rem % 64;
        int col   = ct * 16 + (l & 15);
        int kbase = s * 32 + (l >> 4) * 8;
        bf16x8 sv;
        #pragma unroll
        for (int j = 0; j < 8; ++j) {
            int k = kbase + j;
            sv[j] = f2bf((k < kd) ? W[k * DOUT + col] : 0.0f);
        }
        *(bf16x8*)(dst + (size_t)slot * 8) = sv;
    } else {
        const int tid = threadIdx.x;
        if (tid < DOUT) {
            float acc = bt[tid];
            for (int j = 0; j < DT; ++j)
                acc += cosf(tp[j]) * Wt[j * DOUT + tid];
            tconst[tid] = acc;
        }
    }
}

// ---------------------------------------------------------------------------
// Merged projection GEMM (nodes + edges), persistent + software-pipelined.
// Blocks [0, NBLK_N) do nodes; [NBLK_N, NBLK_N+NBLK_E) do edges (rowmap-gated).
// ---------------------------------------------------------------------------
#define ALOAD(AV, TILE)                                                        \
    {                                                                          \
        const int row0_ = (TILE) * 64 + wv * 16;                               \
        int r_ = row0_ + r15;                                                  \
        if (r_ > nrows - 1) r_ = nrows - 1;                                    \
        const bool live_ = (rowmap == nullptr) || (rowmap[r_] != 0);           \
        const float* fp_ = feat + (size_t)r_ * DN;                             \
        _Pragma("unroll")                                                      \
        for (int s_ = 0; s_ < KSTEPS; ++s_) {                                  \
            const int k0_ = s_ * 32 + kq * 8;                                  \
            AV[2 * s_]     = (f32x4){0, 0, 0, 0};                              \
            AV[2 * s_ + 1] = (f32x4){0, 0, 0, 0};                              \
            if (live_) {                                                       \
                if (k0_ + 4 <= DN) AV[2 * s_]     = *(const f32x4*)(fp_ + k0_);\
                if (k0_ + 8 <= DN) AV[2 * s_ + 1] = *(const f32x4*)(fp_ + k0_ + 4); \
            }                                                                  \
        }                                                                      \
    }

#define CSTORE(AV, TILE)                                                       \
    {                                                                          \
        f32x4 acc_[NCT];                                                       \
        _Pragma("unroll")                                                      \
        for (int ct_ = 0; ct_ < NCT; ++ct_) acc_[ct_] = (f32x4){0, 0, 0, 0};   \
        _Pragma("unroll")                                                      \
        for (int s_ = 0; s_ < KSTEPS; ++s_) {                                  \
            bf16x8 a_;                                                         \
            _Pragma("unroll")                                                  \
            for (int j_ = 0; j_ < 4; ++j_) a_[j_]     = f2bf(AV[2 * s_][j_]);  \
            _Pragma("unroll")                                                  \
            for (int j_ = 0; j_ < 4; ++j_) a_[4 + j_] = f2bf(AV[2 * s_ + 1][j_]); \
            _Pragma("unroll")                                                  \
            for (int ct_ = 0; ct_ < NCT; ++ct_) {                              \
                bf16x8 b_ = *(const bf16x8*)&lds_b[((ct_ * KSTEPS + s_) * 64 + lane) * 8]; \
                acc_[ct_] = __builtin_amdgcn_mfma_f32_16x16x32_bf16(a_, b_, acc_[ct_], 0, 0, 0); \
            }                                                                  \
        }                                                                      \
        const int rbase_ = (TILE) * 64 + wv * 16 + (lane >> 4) * 4;            \
        _Pragma("unroll")                                                      \
        for (int rr_ = 0; rr_ < 4; ++rr_) {                                    \
            const int grow_ = rbase_ + rr_;                                    \
            if (grow_ < nrows && ((rowmap == nullptr) || rowmap[grow_])) {     \
                _Pragma("unroll")                                              \
                for (int ct_ = 0; ct_ < NCT; ++ct_)                            \
                    out[(size_t)grow_ * DOUT + ct_ * 16 + c0] =                \
                        f2bf(acc_[ct_][rr_] + bs[ct_]);                        \
            }                                                                  \
        }                                                                      \
    }

__global__ __launch_bounds__(256)
void k_proj2(const float* __restrict__ featN, const float* __restrict__ biasN,
             const short* __restrict__ wnF, short* __restrict__ outN,
             const float* __restrict__ featE, const float* __restrict__ biasE,
             const short* __restrict__ weF, const unsigned char* __restrict__ emap,
             short* __restrict__ outE)
{
    __shared__ __attribute__((aligned(16))) short lds_b[NCT * KSTEPS * 64 * 8];  // 48 KB
    const int tid = threadIdx.x, lane = tid & 63, wv = tid >> 6;

    const bool edge = (blockIdx.x >= NBLK_N);
    const int  bid  = edge ? blockIdx.x - NBLK_N : blockIdx.x;
    const int  nblk = edge ? NBLK_E : NBLK_N;
    const float* feat = edge ? featE : featN;
    const float* bias = edge ? biasE : biasN;
    const short* wfrag = edge ? weF : wnF;
    const unsigned char* rowmap = edge ? emap : nullptr;
    short* out = edge ? outE : outN;
    const int nrows  = edge ? N_EDGES : N_NODES;
    const int ntiles = (nrows + 63) / 64;

    #pragma unroll
    for (int i = 0; i < 12; ++i)
        ((f32x4*)lds_b)[tid + i * 256] = ((const f32x4*)wfrag)[tid + i * 256];
    __syncthreads();

    const int r15 = lane & 15, kq = lane >> 4, c0 = lane & 15;
    float bs[NCT];
    #pragma unroll
    for (int ct = 0; ct < NCT; ++ct) bs[ct] = bias[ct * 16 + c0];

    int t = bid;
    if (t >= ntiles) return;

    f32x4 avA[2 * KSTEPS], avB[2 * KSTEPS];
    ALOAD(avA, t);
    for (;;) {
        int tn = t + nblk;
        if (tn < ntiles) ALOAD(avB, tn);
        CSTORE(avA, t);
        if (tn >= ntiles) break;
        t = tn;
        tn = t + nblk;
        if (tn < ntiles) ALOAD(avA, tn);
        CSTORE(avB, t);
        if (tn >= ntiles) break;
        t = tn;
    }
}

// ---------------------------------------------------------------------------
// Gather layer. One wave per output row. Indices/times loaded as WAVE-UNIFORM
// scalars (no shuffles); all gather loads issued from SGPR bases + lane offset.
// Writes: partial = src + tconst + (msg_sum + cnt*b_time)/cnt   (bf16 or f32)
//         csum'   = (sum_valid cos_vec) / cnt  as bf16, CSW-wide, zero-padded.
// ---------------------------------------------------------------------------
template <bool L2>
__global__ __launch_bounds__(256)
void k_gather(const short* __restrict__ node_proj, const short* __restrict__ edge_proj,
              const short* __restrict__ nbr_tab,
              const int* __restrict__ src_idx, const float* __restrict__ ts_arr,
              const int* __restrict__ nbrs, const int* __restrict__ eidx,
              const float* __restrict__ etime,
              const float* __restrict__ bt, const float* __restrict__ tw,
              const float* __restrict__ tp, const float* __restrict__ tconst,
              float* __restrict__ partial_f32, short* __restrict__ partial_bf16,
              short* __restrict__ csum_out)
{
    const int tid = threadIdx.x, lane = tid & 63;
    const int wv  = __builtin_amdgcn_readfirstlane(tid >> 6);
    const int row = blockIdx.x * 4 + wv;

    // wave-uniform index/time loads -> SGPRs
    const int*   np_ = nbrs  + (size_t)row * KNBR;
    const int*   ep_ = eidx  + (size_t)row * KNBR;
    const float* tt_ = etime + (size_t)row * KNBR;
    int   nk[KNBR], ek[KNBR];
    float et[KNBR];
    #pragma unroll
    for (int k = 0; k < KNBR; ++k) {
        nk[k] = __builtin_amdgcn_readfirstlane(np_[k]);
        ek[k] = __builtin_amdgcn_readfirstlane(ep_[k]);
        et[k] = rfl_f(tt_[k]);
    }
    const int si = __builtin_amdgcn_readfirstlane(src_idx[row]);
    const float ts = rfl_f(L2 ? ts_arr[row] : ts_arr[row / KNBR]);

    int cnt = 0;
    #pragma unroll
    for (int k = 0; k < KNBR; ++k) cnt += (nk[k] != 0);

    const int d2 = lane * 2;
    // issue every gather before any compute
    uint32_t ev[KNBR], nv[KNBR];
    #pragma unroll
    for (int k = 0; k < KNBR; ++k)
        ev[k] = *(const uint32_t*)(edge_proj + (size_t)ek[k] * DOUT + d2);
    #pragma unroll
    for (int k = 0; k < KNBR; ++k) {
        size_t ri = L2 ? ((size_t)row * KNBR + k) : (size_t)nk[k];
        nv[k] = *(const uint32_t*)(nbr_tab + ri * DOUT + d2);
    }
    const uint32_t sv  = *(const uint32_t*)(node_proj + (size_t)si * DOUT + d2);
    const f32x2    bt2 = *(const f32x2*)&bt[d2];
    const f32x2    tc2 = *(const f32x2*)&tconst[d2];

    const float wr0 = tw[lane] * INV2PI;
    float base0 = fmaf(ts, wr0, tp[lane] * INV2PI);
    float wr1 = 0.0f, base1 = 0.0f;
    if (lane < DT - 64) {
        wr1   = tw[64 + lane] * INV2PI;
        base1 = fmaf(ts, wr1, tp[64 + lane] * INV2PI);
    }

    float cs0 = 0, cs1 = 0, ms0 = 0, ms1 = 0;
    #pragma unroll
    for (int k = 0; k < KNBR; ++k) {
        const float w = (nk[k] != 0) ? 1.0f : 0.0f;
        float r0 = fmaf(-et[k], wr0, base0); r0 -= floorf(r0);
        float r1 = fmaf(-et[k], wr1, base1); r1 -= floorf(r1);
        cs0 = fmaf(w, __builtin_amdgcn_cosf(r0), cs0);
        cs1 = fmaf(w, __builtin_amdgcn_cosf(r1), cs1);
        ms0 = fmaf(w, bflo(ev[k]) + bflo(nv[k]), ms0);
        ms1 = fmaf(w, bfhi(ev[k]) + bfhi(nv[k]), ms1);
    }

    const float fc  = (float)cnt;
    const float inv = (cnt > 0) ? 1.0f / fc : 1.0f;

    csum_out[(size_t)row * CSW + lane] = f2bf(cs0 * inv);
    if (lane < 48)
        csum_out[(size_t)row * CSW + 64 + lane] = f2bf(lane < DT - 64 ? cs1 * inv : 0.0f);

    const float o0 = bflo(sv) + tc2[0] + (ms0 + fc * bt2[0]) * inv;
    const float o1 = bfhi(sv) + tc2[1] + (ms1 + fc * bt2[1]) * inv;
    if (L2) {
        *(f32x2*)(partial_f32 + (size_t)row * DOUT + d2) = (f32x2){o0, o1};
    } else {
        uint32_t u = (uint32_t)(uint16_t)f2bf(o0) | ((uint32_t)(uint16_t)f2bf(o1) << 16);
        *(uint32_t*)(partial_bf16 + (size_t)row * DOUT + d2) = u;
    }
}

// ---------------------------------------------------------------------------
// Time GEMM: io[row][c] += csum'[row][:] @ W_time[:,c]   (in-place RMW).
// ---------------------------------------------------------------------------
template <bool F32IO>
__global__ __launch_bounds__(256)
void k_tgemm(const short* __restrict__ csum, const short* __restrict__ wtF,
             float* __restrict__ io_f32, short* __restrict__ io_bf16,
             int nrows, int ntiles)
{
    __shared__ __attribute__((aligned(16))) short lds_b[NCT * KSTEPS_T * 64 * 8];  // 32 KB
    const int tid = threadIdx.x, lane = tid & 63, wv = tid >> 6;

    #pragma unroll
    for (int i = 0; i < 8; ++i)
        ((f32x4*)lds_b)[tid + i * 256] = ((const f32x4*)wtF)[tid + i * 256];
    __syncthreads();

    const int r15 = lane & 15, kq = lane >> 4, c0 = lane & 15;

    for (int tile = blockIdx.x; tile < ntiles; tile += gridDim.x) {
        const int row0 = tile * 64 + wv * 16;
        int r = row0 + r15;
        if (r > nrows - 1) r = nrows - 1;
        const short* ap = csum + (size_t)r * CSW;

        f32x4 acc[NCT];
        #pragma unroll
        for (int ct = 0; ct < NCT; ++ct) acc[ct] = (f32x4){0, 0, 0, 0};

        #pragma unroll
        for (int s = 0; s < KSTEPS_T; ++s) {
            const int k0 = s * 32 + kq * 8;
            bf16x8 a = (bf16x8)(short)0;
            if (k0 + 8 <= CSW) a = *(const bf16x8*)(ap + k0);
            #pragma unroll
            for (int ct = 0; ct < NCT; ++ct) {
                bf16x8 b = *(const bf16x8*)&lds_b[((ct * KSTEPS_T + s) * 64 + lane) * 8];
                acc[ct] = __builtin_amdgcn_mfma_f32_16x16x32_bf16(a, b, acc[ct], 0, 0, 0);
            }
        }
        const int rbase = row0 + (lane >> 4) * 4;
        #pragma unroll
        for (int ct = 0; ct < NCT; ++ct) {
            const int c = ct * 16 + c0;
            #pragma unroll
            for (int rr = 0; rr < 4; ++rr) {
                int grow = rbase + rr;
                if (grow < nrows) {
                    size_t off = (size_t)grow * DOUT + c;
                    if (F32IO) {
                        io_f32[off] += acc[ct][rr];
                    } else {
                        float oldv = bflo((uint32_t)(uint16_t)io_bf16[off]);
                        io_bf16[off] = f2bf(oldv + acc[ct][rr]);
                    }
                }
            }
        }
    }
}

// ---------------------------------------------------------------------------
extern "C" void kernel_launch(void* const* d_in, const int* in_sizes, int n_in,
                              void* d_out, int out_size, void* d_ws, size_t ws_size,
                              hipStream_t stream)
{
    const float* node_features = (const float*)d_in[0];
    const float* edge_features = (const float*)d_in[1];
    const float* W_node  = (const float*)d_in[2];
    const float* b_node  = (const float*)d_in[3];
    const float* W_time  = (const float*)d_in[4];
    const float* b_time  = (const float*)d_in[5];
    const float* W_edge  = (const float*)d_in[6];
    const float* b_edge  = (const float*)d_in[7];
    const float* time_w  = (const float*)d_in[8];
    const float* time_ph = (const float*)d_in[9];
    const int*   source_nodes = (const int*)d_in[10];
    const float* timestamps   = (const float*)d_in[11];
    const int*   nbrs_l2  = (const int*)d_in[12];
    const int*   eidx_l2  = (const int*)d_in[13];
    const float* etime_l2 = (const float*)d_in[14];
    const int*   nbrs_l1  = (const int*)d_in[15];
    const int*   eidx_l1  = (const int*)d_in[16];
    const float* etime_l1 = (const float*)d_in[17];

    // workspace layout (all offsets 256B-aligned)
    char*  ws        = (char*)d_ws;
    short* node_proj = (short*)(ws);                    // 128,000,000
    short* edge_proj = (short*)(ws + 128000000);        // 256,000,000
    short* emb1      = (short*)(ws + 384000000);        //  20,971,520 (bf16)
    short* csum1     = (short*)(ws + 404971520);        //  18,350,080
    short* csum2     = (short*)(ws + 423321600);        //     917,504
    float* tconst    = (float*)(ws + 424239104);        //         512
    short* wnF       = (short*)(ws + 424239616);        //      49,152
    short* weF       = (short*)(ws + 424288768);        //      49,152
    short* wtF       = (short*)(ws + 424337920);        //      32,768
    unsigned char* emap = (unsigned char*)(ws + 424371200); // 1,000,000 -> 425,371,200
    if (ws_size < 425500000ull) return;

    k_zero<<<128, 256, 0, stream>>>((uint32_t*)emap, N_EDGES / 4);
    k_mark<<<512, 256, 0, stream>>>(eidx_l1, eidx_l2, emap);
    k_prep<<<33, 256, 0, stream>>>(W_node, W_edge, W_time, b_time, time_ph,
                                   wnF, weF, wtF, tconst);

    k_proj2<<<NBLK_N + NBLK_E, 256, 0, stream>>>(
        node_features, b_node, wnF, node_proj,
        edge_features, b_edge, weF, emap, edge_proj);

    // layer 1: rows = B*K; nbrs gathered from node_proj; partial -> emb1 (bf16)
    k_gather<false><<<(BATCH * KNBR) / 4, 256, 0, stream>>>(
        node_proj, edge_proj, node_proj, nbrs_l2,
        timestamps, nbrs_l1, eidx_l1, etime_l1,
        b_time, time_w, time_ph, tconst,
        nullptr, emb1, csum1);
    {
        int nt = (BATCH * KNBR + 63) / 64;
        k_tgemm<false><<<nt, 256, 0, stream>>>(csum1, wtF, nullptr, emb1, BATCH * KNBR, nt);
    }

    // layer 2: rows = B; nbrs from contiguous emb1 (bf16); partial -> d_out (f32)
    k_gather<true><<<BATCH / 4, 256, 0, stream>>>(
        node_proj, edge_proj, emb1, source_nodes,
        timestamps, nbrs_l2, eidx_l2, etime_l2,
        b_time, time_w, time_ph, tconst,
        (float*)d_out, nullptr, csum2);
    {
        int nt = (BATCH + 63) / 64;
        k_tgemm<true><<<nt, 256, 0, stream>>>(csum2, wtF, (float*)d_out, nullptr, BATCH, nt);
    }
}

// Round 7
// 479.729 us; speedup vs baseline: 2.4614x; 1.1562x over previous
//
#include <hip/hip_runtime.h>
#include <hip/hip_bf16.h>
#include <stdint.h>
#include <string.h>

#define N_NODES 500000
#define N_EDGES 1000000
#define BATCH   4096
#define KNBR    20
#define DN      172
#define DT      100
#define DOUT    128

#define KSTEPS   6    // ceil(172/32)
#define KSTEPS_T 4    // ceil(100/32) padded to 128
#define NCT      8    // 128 / 16 col tiles
#define CSW      112  // csum row width (bf16), 224 B, 16B-aligned

#define NMARK   (BATCH * KNBR * KNBR + BATCH * KNBR)   // 1,720,320 edge refs

#define NBLK_N  896
#define NBLK_E  1152

typedef __attribute__((ext_vector_type(8))) short   bf16x8;
typedef __attribute__((ext_vector_type(4))) float   f32x4;
typedef __attribute__((ext_vector_type(2))) float   f32x2;

#define INV2PI 0.15915494309189535f

__device__ inline short f2bf(float f) {
    __hip_bfloat16 h = __float2bfloat16(f);
    short s;
    memcpy(&s, &h, 2);
    return s;
}
__device__ inline float bflo(uint32_t u) { return __uint_as_float(u << 16); }
__device__ inline float bfhi(uint32_t u) { return __uint_as_float(u & 0xffff0000u); }
__device__ inline float rfl_f(float x) {
    return __uint_as_float(__builtin_amdgcn_readfirstlane(__float_as_uint(x)));
}
// fp8 e4m3 (OCP on gfx950) pack/unpack via HW converts
__device__ inline unsigned char f2fp8(float f) {
    return (unsigned char)(__builtin_amdgcn_cvt_pk_fp8_f32(f, f, 0, false) & 0xff);
}
__device__ inline f32x2 fp8pair(uint32_t u) {   // low 16 bits = 2 fp8 values
    f32x2 r = __builtin_amdgcn_cvt_pk_f32_fp8((int)u, false);
    return r;
}

// ---------------------------------------------------------------------------
__global__ void k_zero(uint32_t* __restrict__ p, int ndw)
{
    for (int i = blockIdx.x * blockDim.x + threadIdx.x; i < ndw;
         i += gridDim.x * blockDim.x)
        p[i] = 0;
}

__global__ void k_mark(const int* __restrict__ e1, const int* __restrict__ e2,
                       unsigned char* __restrict__ emap)
{
    const int n1 = BATCH * KNBR * KNBR;
    for (int i = blockIdx.x * blockDim.x + threadIdx.x; i < NMARK;
         i += gridDim.x * blockDim.x) {
        int e = (i < n1) ? e1[i] : e2[i - n1];
        emap[e] = 1;
    }
}

// ---------------------------------------------------------------------------
// Prep: blocks 0..31 build B-fragment arrays, block 32 computes tconst.
// B-frag slot (ct, s, lane): col = ct*16 + (lane&15), k = s*32 + (lane>>4)*8 + j
// ---------------------------------------------------------------------------
__global__ void k_prep(const float* __restrict__ Wn, const float* __restrict__ We,
                       const float* __restrict__ Wt, const float* __restrict__ bt,
                       const float* __restrict__ tp,
                       short* __restrict__ wnF, short* __restrict__ weF,
                       short* __restrict__ wtF, float* __restrict__ tconst)
{
    const int NS6 = NCT * KSTEPS * 64;    // 3072
    const int NS4 = NCT * KSTEPS_T * 64;  // 2048
    if (blockIdx.x < 32) {
        const int idx = blockIdx.x * 256 + threadIdx.x;   // 8192 = 2*NS6+NS4
        const float* W;
        short* dst;
        int slot, ks;
        if (idx < NS6)          { W = Wn; dst = wnF; slot = idx;           ks = KSTEPS; }
        else if (idx < 2 * NS6) { W = We; dst = weF; slot = idx - NS6;     ks = KSTEPS; }
        else                    { W = Wt; dst = wtF; slot = idx - 2 * NS6; ks = KSTEPS_T; }
        const int kd = (ks == KSTEPS) ? DN : DT;
        int ct  = slot / (ks * 64);
        int rem = slot % (ks * 64);
        int s   = rem / 64;
        int l   = rem % 64;
        int col   = ct * 16 + (l & 15);
        int kbase = s * 32 + (l >> 4) * 8;
        bf16x8 sv;
        #pragma unroll
        for (int j = 0; j < 8; ++j) {
            int k = kbase + j;
            sv[j] = f2bf((k < kd) ? W[k * DOUT + col] : 0.0f);
        }
        *(bf16x8*)(dst + (size_t)slot * 8) = sv;
    } else {
        const int tid = threadIdx.x;
        if (tid < DOUT) {
            float acc = bt[tid];
            for (int j = 0; j < DT; ++j)
                acc += cosf(tp[j]) * Wt[j * DOUT + tid];
            tconst[tid] = acc;
        }
    }
}

// ---------------------------------------------------------------------------
// Merged projection GEMM (nodes + edges), persistent + software-pipelined.
// Nodes: write bf16 table (for src reads) + fp8 table (for message gathers).
// Edges: write fp8 table only, rowmap-gated.
// ---------------------------------------------------------------------------
#define ALOAD(AV, TILE)                                                        \
    {                                                                          \
        const int row0_ = (TILE) * 64 + wv * 16;                               \
        int r_ = row0_ + r15;                                                  \
        if (r_ > nrows - 1) r_ = nrows - 1;                                    \
        const bool live_ = (rowmap == nullptr) || (rowmap[r_] != 0);           \
        const float* fp_ = feat + (size_t)r_ * DN;                             \
        _Pragma("unroll")                                                      \
        for (int s_ = 0; s_ < KSTEPS; ++s_) {                                  \
            const int k0_ = s_ * 32 + kq * 8;                                  \
            AV[2 * s_]     = (f32x4){0, 0, 0, 0};                              \
            AV[2 * s_ + 1] = (f32x4){0, 0, 0, 0};                              \
            if (live_) {                                                       \
                if (k0_ + 4 <= DN) AV[2 * s_]     = *(const f32x4*)(fp_ + k0_);\
                if (k0_ + 8 <= DN) AV[2 * s_ + 1] = *(const f32x4*)(fp_ + k0_ + 4); \
            }                                                                  \
        }                                                                      \
    }

#define CSTORE(AV, TILE)                                                       \
    {                                                                          \
        f32x4 acc_[NCT];                                                       \
        _Pragma("unroll")                                                      \
        for (int ct_ = 0; ct_ < NCT; ++ct_) acc_[ct_] = (f32x4){0, 0, 0, 0};   \
        _Pragma("unroll")                                                      \
        for (int s_ = 0; s_ < KSTEPS; ++s_) {                                  \
            bf16x8 a_;                                                         \
            _Pragma("unroll")                                                  \
            for (int j_ = 0; j_ < 4; ++j_) a_[j_]     = f2bf(AV[2 * s_][j_]);  \
            _Pragma("unroll")                                                  \
            for (int j_ = 0; j_ < 4; ++j_) a_[4 + j_] = f2bf(AV[2 * s_ + 1][j_]); \
            _Pragma("unroll")                                                  \
            for (int ct_ = 0; ct_ < NCT; ++ct_) {                              \
                bf16x8 b_ = *(const bf16x8*)&lds_b[((ct_ * KSTEPS + s_) * 64 + lane) * 8]; \
                acc_[ct_] = __builtin_amdgcn_mfma_f32_16x16x32_bf16(a_, b_, acc_[ct_], 0, 0, 0); \
            }                                                                  \
        }                                                                      \
        const int rbase_ = (TILE) * 64 + wv * 16 + (lane >> 4) * 4;            \
        _Pragma("unroll")                                                      \
        for (int rr_ = 0; rr_ < 4; ++rr_) {                                    \
            const int grow_ = rbase_ + rr_;                                    \
            if (grow_ < nrows && ((rowmap == nullptr) || rowmap[grow_])) {     \
                _Pragma("unroll")                                              \
                for (int ct_ = 0; ct_ < NCT; ++ct_) {                          \
                    const float v_ = acc_[ct_][rr_] + bs[ct_];                 \
                    out8[(size_t)grow_ * DOUT + ct_ * 16 + c0] = f2fp8(v_);    \
                    if (out16)                                                 \
                        out16[(size_t)grow_ * DOUT + ct_ * 16 + c0] = f2bf(v_);\
                }                                                              \
            }                                                                  \
        }                                                                      \
    }

__global__ __launch_bounds__(256)
void k_proj2(const float* __restrict__ featN, const float* __restrict__ biasN,
             const short* __restrict__ wnF, short* __restrict__ nodeBF,
             unsigned char* __restrict__ nodeF8,
             const float* __restrict__ featE, const float* __restrict__ biasE,
             const short* __restrict__ weF, const unsigned char* __restrict__ emap,
             unsigned char* __restrict__ edgeF8)
{
    __shared__ __attribute__((aligned(16))) short lds_b[NCT * KSTEPS * 64 * 8];  // 48 KB
    const int tid = threadIdx.x, lane = tid & 63, wv = tid >> 6;

    const bool edge = (blockIdx.x >= NBLK_N);
    const int  bid  = edge ? blockIdx.x - NBLK_N : blockIdx.x;
    const int  nblk = edge ? NBLK_E : NBLK_N;
    const float* feat = edge ? featE : featN;
    const float* bias = edge ? biasE : biasN;
    const short* wfrag = edge ? weF : wnF;
    const unsigned char* rowmap = edge ? emap : nullptr;
    unsigned char* out8 = edge ? edgeF8 : nodeF8;
    short* out16 = edge ? nullptr : nodeBF;
    const int nrows  = edge ? N_EDGES : N_NODES;
    const int ntiles = (nrows + 63) / 64;

    #pragma unroll
    for (int i = 0; i < 12; ++i)
        ((f32x4*)lds_b)[tid + i * 256] = ((const f32x4*)wfrag)[tid + i * 256];
    __syncthreads();

    const int r15 = lane & 15, kq = lane >> 4, c0 = lane & 15;
    float bs[NCT];
    #pragma unroll
    for (int ct = 0; ct < NCT; ++ct) bs[ct] = bias[ct * 16 + c0];

    int t = bid;
    if (t >= ntiles) return;

    f32x4 avA[2 * KSTEPS], avB[2 * KSTEPS];
    ALOAD(avA, t);
    for (;;) {
        int tn = t + nblk;
        if (tn < ntiles) ALOAD(avB, tn);
        CSTORE(avA, t);
        if (tn >= ntiles) break;
        t = tn;
        tn = t + nblk;
        if (tn < ntiles) ALOAD(avA, tn);
        CSTORE(avB, t);
        if (tn >= ntiles) break;
        t = tn;
    }
}

// ---------------------------------------------------------------------------
// Gather layer. One wave per output row; wave-uniform scalar indices.
// Messages read as fp8 (edge always; node table for L1). Src read bf16.
// L2 neighbor rows come from contiguous bf16 emb1.
// ---------------------------------------------------------------------------
template <bool L2>
__global__ __launch_bounds__(256)
void k_gather(const short* __restrict__ node_bf16, const unsigned char* __restrict__ edge_f8,
              const unsigned char* __restrict__ node_f8, const short* __restrict__ emb1_tab,
              const int* __restrict__ src_idx, const float* __restrict__ ts_arr,
              const int* __restrict__ nbrs, const int* __restrict__ eidx,
              const float* __restrict__ etime,
              const float* __restrict__ bt, const float* __restrict__ tw,
              const float* __restrict__ tp, const float* __restrict__ tconst,
              float* __restrict__ partial_f32, short* __restrict__ partial_bf16,
              short* __restrict__ csum_out)
{
    const int tid = threadIdx.x, lane = tid & 63;
    const int wv  = __builtin_amdgcn_readfirstlane(tid >> 6);
    const int row = blockIdx.x * 4 + wv;

    // wave-uniform index/time loads -> SGPRs
    const int*   np_ = nbrs  + (size_t)row * KNBR;
    const int*   ep_ = eidx  + (size_t)row * KNBR;
    const float* tt_ = etime + (size_t)row * KNBR;
    int   nk[KNBR], ek[KNBR];
    float et[KNBR];
    #pragma unroll
    for (int k = 0; k < KNBR; ++k) {
        nk[k] = __builtin_amdgcn_readfirstlane(np_[k]);
        ek[k] = __builtin_amdgcn_readfirstlane(ep_[k]);
        et[k] = rfl_f(tt_[k]);
    }
    const int si = __builtin_amdgcn_readfirstlane(src_idx[row]);
    const float ts = rfl_f(L2 ? ts_arr[row] : ts_arr[row / KNBR]);

    int cnt = 0;
    #pragma unroll
    for (int k = 0; k < KNBR; ++k) cnt += (nk[k] != 0);

    const int d2 = lane * 2;
    // issue every gather before any compute
    uint32_t ev[KNBR], nv[KNBR];
    #pragma unroll
    for (int k = 0; k < KNBR; ++k)
        ev[k] = *(const uint16_t*)(edge_f8 + (size_t)ek[k] * DOUT + d2);
    #pragma unroll
    for (int k = 0; k < KNBR; ++k) {
        if (L2) nv[k] = *(const uint32_t*)(emb1_tab + ((size_t)row * KNBR + k) * DOUT + d2);
        else    nv[k] = *(const uint16_t*)(node_f8 + (size_t)nk[k] * DOUT + d2);
    }
    const uint32_t sv  = *(const uint32_t*)(node_bf16 + (size_t)si * DOUT + d2);
    const f32x2    bt2 = *(const f32x2*)&bt[d2];
    const f32x2    tc2 = *(const f32x2*)&tconst[d2];

    const float wr0 = tw[lane] * INV2PI;
    float base0 = fmaf(ts, wr0, tp[lane] * INV2PI);
    float wr1 = 0.0f, base1 = 0.0f;
    if (lane < DT - 64) {
        wr1   = tw[64 + lane] * INV2PI;
        base1 = fmaf(ts, wr1, tp[64 + lane] * INV2PI);
    }

    float cs0 = 0, cs1 = 0, ms0 = 0, ms1 = 0;
    #pragma unroll
    for (int k = 0; k < KNBR; ++k) {
        const float w = (nk[k] != 0) ? 1.0f : 0.0f;
        float r0 = fmaf(-et[k], wr0, base0); r0 -= floorf(r0);
        float r1 = fmaf(-et[k], wr1, base1); r1 -= floorf(r1);
        cs0 = fmaf(w, __builtin_amdgcn_cosf(r0), cs0);
        cs1 = fmaf(w, __builtin_amdgcn_cosf(r1), cs1);
        f32x2 e2 = fp8pair(ev[k]);
        float nlo, nhi;
        if (L2) { nlo = bflo(nv[k]); nhi = bfhi(nv[k]); }
        else    { f32x2 n2 = fp8pair(nv[k]); nlo = n2[0]; nhi = n2[1]; }
        ms0 = fmaf(w, e2[0] + nlo, ms0);
        ms1 = fmaf(w, e2[1] + nhi, ms1);
    }

    const float fc  = (float)cnt;
    const float inv = (cnt > 0) ? 1.0f / fc : 1.0f;

    csum_out[(size_t)row * CSW + lane] = f2bf(cs0 * inv);
    if (lane < 48)
        csum_out[(size_t)row * CSW + 64 + lane] = f2bf(lane < DT - 64 ? cs1 * inv : 0.0f);

    const float o0 = bflo(sv) + tc2[0] + (ms0 + fc * bt2[0]) * inv;
    const float o1 = bfhi(sv) + tc2[1] + (ms1 + fc * bt2[1]) * inv;
    if (L2) {
        *(f32x2*)(partial_f32 + (size_t)row * DOUT + d2) = (f32x2){o0, o1};
    } else {
        uint32_t u = (uint32_t)(uint16_t)f2bf(o0) | ((uint32_t)(uint16_t)f2bf(o1) << 16);
        *(uint32_t*)(partial_bf16 + (size_t)row * DOUT + d2) = u;
    }
}

// ---------------------------------------------------------------------------
// Time GEMM: io[row][c] += csum'[row][:] @ W_time[:,c]   (in-place RMW).
// ---------------------------------------------------------------------------
template <bool F32IO>
__global__ __launch_bounds__(256)
void k_tgemm(const short* __restrict__ csum, const short* __restrict__ wtF,
             float* __restrict__ io_f32, short* __restrict__ io_bf16,
             int nrows, int ntiles)
{
    __shared__ __attribute__((aligned(16))) short lds_b[NCT * KSTEPS_T * 64 * 8];  // 32 KB
    const int tid = threadIdx.x, lane = tid & 63, wv = tid >> 6;

    #pragma unroll
    for (int i = 0; i < 8; ++i)
        ((f32x4*)lds_b)[tid + i * 256] = ((const f32x4*)wtF)[tid + i * 256];
    __syncthreads();

    const int r15 = lane & 15, kq = lane >> 4, c0 = lane & 15;

    for (int tile = blockIdx.x; tile < ntiles; tile += gridDim.x) {
        const int row0 = tile * 64 + wv * 16;
        int r = row0 + r15;
        if (r > nrows - 1) r = nrows - 1;
        const short* ap = csum + (size_t)r * CSW;

        f32x4 acc[NCT];
        #pragma unroll
        for (int ct = 0; ct < NCT; ++ct) acc[ct] = (f32x4){0, 0, 0, 0};

        #pragma unroll
        for (int s = 0; s < KSTEPS_T; ++s) {
            const int k0 = s * 32 + kq * 8;
            bf16x8 a = (bf16x8)(short)0;
            if (k0 + 8 <= CSW) a = *(const bf16x8*)(ap + k0);
            #pragma unroll
            for (int ct = 0; ct < NCT; ++ct) {
                bf16x8 b = *(const bf16x8*)&lds_b[((ct * KSTEPS_T + s) * 64 + lane) * 8];
                acc[ct] = __builtin_amdgcn_mfma_f32_16x16x32_bf16(a, b, acc[ct], 0, 0, 0);
            }
        }
        const int rbase = row0 + (lane >> 4) * 4;
        #pragma unroll
        for (int ct = 0; ct < NCT; ++ct) {
            const int c = ct * 16 + c0;
            #pragma unroll
            for (int rr = 0; rr < 4; ++rr) {
                int grow = rbase + rr;
                if (grow < nrows) {
                    size_t off = (size_t)grow * DOUT + c;
                    if (F32IO) {
                        io_f32[off] += acc[ct][rr];
                    } else {
                        float oldv = bflo((uint32_t)(uint16_t)io_bf16[off]);
                        io_bf16[off] = f2bf(oldv + acc[ct][rr]);
                    }
                }
            }
        }
    }
}

// ---------------------------------------------------------------------------
extern "C" void kernel_launch(void* const* d_in, const int* in_sizes, int n_in,
                              void* d_out, int out_size, void* d_ws, size_t ws_size,
                              hipStream_t stream)
{
    const float* node_features = (const float*)d_in[0];
    const float* edge_features = (const float*)d_in[1];
    const float* W_node  = (const float*)d_in[2];
    const float* b_node  = (const float*)d_in[3];
    const float* W_time  = (const float*)d_in[4];
    const float* b_time  = (const float*)d_in[5];
    const float* W_edge  = (const float*)d_in[6];
    const float* b_edge  = (const float*)d_in[7];
    const float* time_w  = (const float*)d_in[8];
    const float* time_ph = (const float*)d_in[9];
    const int*   source_nodes = (const int*)d_in[10];
    const float* timestamps   = (const float*)d_in[11];
    const int*   nbrs_l2  = (const int*)d_in[12];
    const int*   eidx_l2  = (const int*)d_in[13];
    const float* etime_l2 = (const float*)d_in[14];
    const int*   nbrs_l1  = (const int*)d_in[15];
    const int*   eidx_l1  = (const int*)d_in[16];
    const float* etime_l1 = (const float*)d_in[17];

    // workspace layout (all offsets 256B-aligned)
    char*  ws        = (char*)d_ws;
    short* node_bf16 = (short*)(ws);                        // 128,000,000
    unsigned char* edge_f8 = (unsigned char*)(ws + 128000000);  // 128,000,000
    unsigned char* node_f8 = (unsigned char*)(ws + 256000000);  //  64,000,000
    short* emb1      = (short*)(ws + 320000000);            //  20,971,520 (bf16)
    short* csum1     = (short*)(ws + 340971520);            //  18,350,080
    short* csum2     = (short*)(ws + 359321600);            //     917,504
    float* tconst    = (float*)(ws + 360239104);            //         512
    short* wnF       = (short*)(ws + 360239616);            //      49,152
    short* weF       = (short*)(ws + 360288768);            //      49,152
    short* wtF       = (short*)(ws + 360337920);            //      32,768
    unsigned char* emap = (unsigned char*)(ws + 360371200); //   1,000,000 -> 361,371,200
    if (ws_size < 361500000ull) return;

    k_zero<<<128, 256, 0, stream>>>((uint32_t*)emap, N_EDGES / 4);
    k_mark<<<512, 256, 0, stream>>>(eidx_l1, eidx_l2, emap);
    k_prep<<<33, 256, 0, stream>>>(W_node, W_edge, W_time, b_time, time_ph,
                                   wnF, weF, wtF, tconst);

    k_proj2<<<NBLK_N + NBLK_E, 256, 0, stream>>>(
        node_features, b_node, wnF, node_bf16, node_f8,
        edge_features, b_edge, weF, emap, edge_f8);

    // layer 1: rows = B*K; fp8 msg gathers; partial -> emb1 (bf16)
    k_gather<false><<<(BATCH * KNBR) / 4, 256, 0, stream>>>(
        node_bf16, edge_f8, node_f8, emb1, nbrs_l2,
        timestamps, nbrs_l1, eidx_l1, etime_l1,
        b_time, time_w, time_ph, tconst,
        nullptr, emb1, csum1);
    {
        int nt = (BATCH * KNBR + 63) / 64;
        k_tgemm<false><<<nt, 256, 0, stream>>>(csum1, wtF, nullptr, emb1, BATCH * KNBR, nt);
    }

    // layer 2: rows = B; edge fp8 + emb1 bf16; partial -> d_out (f32)
    k_gather<true><<<BATCH / 4, 256, 0, stream>>>(
        node_bf16, edge_f8, node_f8, emb1, source_nodes,
        timestamps, nbrs_l2, eidx_l2, etime_l2,
        b_time, time_w, time_ph, tconst,
        (float*)d_out, nullptr, csum2);
    {
        int nt = (BATCH + 63) / 64;
        k_tgemm<true><<<nt, 256, 0, stream>>>(csum2, wtF, (float*)d_out, nullptr, BATCH, nt);
    }
}

// Round 8
// 448.947 us; speedup vs baseline: 2.6302x; 1.0686x over previous
//
#include <hip/hip_runtime.h>
#include <hip/hip_bf16.h>
#include <stdint.h>
#include <string.h>

#define N_NODES 500000
#define N_EDGES 1000000
#define BATCH   4096
#define KNBR    20
#define DN      172
#define DT      100
#define DOUT    128

#define KSTEPS   6    // ceil(172/32)
#define KSTEPS_T 4    // ceil(100/32) padded to 128
#define NCT      8    // 128 / 16 col tiles
#define CSW      112  // csum row width (bf16), 224 B, 16B-aligned

#define NMARK_E (BATCH * KNBR * KNBR + BATCH * KNBR)   // 1,720,320 edge refs
#define NMARK_N (BATCH * KNBR + BATCH)                 //    86,016 node src refs

#define NBLK_N  800
#define NBLK_E  1248

typedef __attribute__((ext_vector_type(8))) short   bf16x8;
typedef __attribute__((ext_vector_type(4))) float   f32x4;
typedef __attribute__((ext_vector_type(2))) float   f32x2;

#define INV2PI 0.15915494309189535f

__device__ inline short f2bf(float f) {
    __hip_bfloat16 h = __float2bfloat16(f);
    short s;
    memcpy(&s, &h, 2);
    return s;
}
__device__ inline float bflo(uint32_t u) { return __uint_as_float(u << 16); }
__device__ inline float bfhi(uint32_t u) { return __uint_as_float(u & 0xffff0000u); }
__device__ inline float rfl_f(float x) {
    return __uint_as_float(__builtin_amdgcn_readfirstlane(__float_as_uint(x)));
}
// fp8 e4m3 (OCP on gfx950) pack/unpack via HW converts
__device__ inline unsigned char f2fp8(float f) {
    return (unsigned char)(__builtin_amdgcn_cvt_pk_fp8_f32(f, f, 0, false) & 0xff);
}
__device__ inline f32x2 fp8pair(uint32_t u) {   // low 16 bits = 2 fp8 values
    return __builtin_amdgcn_cvt_pk_f32_fp8((int)u, false);
}

// ---------------------------------------------------------------------------
// Prep (one launch). Block roles:
//   [0,32)    : B-fragment build (1 slot/thread)
//   32        : tconst = cos(phase) @ W_time + b_time
//   [33,545)  : edge liveness mark (emap)
//   [545,577) : node src-row mark (nmap): nbrs_l2 + source_nodes
// emap/nmap zeroed by hipMemsetAsync before this kernel.
// ---------------------------------------------------------------------------
__global__ void k_prep(const float* __restrict__ Wn, const float* __restrict__ We,
                       const float* __restrict__ Wt, const float* __restrict__ bt,
                       const float* __restrict__ tp,
                       const int* __restrict__ e1, const int* __restrict__ e2,
                       const int* __restrict__ srcs1, const int* __restrict__ srcs2,
                       short* __restrict__ wnF, short* __restrict__ weF,
                       short* __restrict__ wtF, float* __restrict__ tconst,
                       unsigned char* __restrict__ emap, unsigned char* __restrict__ nmap)
{
    const int NS6 = NCT * KSTEPS * 64;    // 3072
    const int NS4 = NCT * KSTEPS_T * 64;  // 2048
    const int b = blockIdx.x;
    if (b < 32) {
        const int idx = b * 256 + threadIdx.x;   // 8192 = 2*NS6+NS4
        const float* W;
        short* dst;
        int slot, ks;
        if (idx < NS6)          { W = Wn; dst = wnF; slot = idx;           ks = KSTEPS; }
        else if (idx < 2 * NS6) { W = We; dst = weF; slot = idx - NS6;     ks = KSTEPS; }
        else                    { W = Wt; dst = wtF; slot = idx - 2 * NS6; ks = KSTEPS_T; }
        const int kd = (ks == KSTEPS) ? DN : DT;
        int ct  = slot / (ks * 64);
        int rem = slot % (ks * 64);
        int s   = rem / 64;
        int l   = rem % 64;
        int col   = ct * 16 + (l & 15);
        int kbase = s * 32 + (l >> 4) * 8;
        bf16x8 sv;
        #pragma unroll
        for (int j = 0; j < 8; ++j) {
            int k = kbase + j;
            sv[j] = f2bf((k < kd) ? W[k * DOUT + col] : 0.0f);
        }
        *(bf16x8*)(dst + (size_t)slot * 8) = sv;
    } else if (b == 32) {
        const int tid = threadIdx.x;
        if (tid < DOUT) {
            float acc = bt[tid];
            for (int j = 0; j < DT; ++j)
                acc += cosf(tp[j]) * Wt[j * DOUT + tid];
            tconst[tid] = acc;
        }
    } else if (b < 545) {
        const int n1 = BATCH * KNBR * KNBR;
        for (int i = (b - 33) * 256 + threadIdx.x; i < NMARK_E; i += 512 * 256) {
            int e = (i < n1) ? e1[i] : e2[i - n1];
            emap[e] = 1;
        }
    } else {
        const int n1 = BATCH * KNBR;
        for (int i = (b - 545) * 256 + threadIdx.x; i < NMARK_N; i += 32 * 256) {
            int n = (i < n1) ? srcs1[i] : srcs2[i - n1];
            nmap[n] = 1;
        }
    }
}

// ---------------------------------------------------------------------------
// Merged projection GEMM (nodes + edges), persistent + software-pipelined.
// Nodes: fp8 table for all rows; bf16 table ONLY for nmap-marked rows.
// Edges: fp8 table only, emap-gated (loads and stores skipped for dead rows).
// ---------------------------------------------------------------------------
#define ALOAD(AV, TILE)                                                        \
    {                                                                          \
        const int row0_ = (TILE) * 64 + wv * 16;                               \
        int r_ = row0_ + r15;                                                  \
        if (r_ > nrows - 1) r_ = nrows - 1;                                    \
        const bool live_ = (rowmap == nullptr) || (rowmap[r_] != 0);           \
        const float* fp_ = feat + (size_t)r_ * DN;                             \
        _Pragma("unroll")                                                      \
        for (int s_ = 0; s_ < KSTEPS; ++s_) {                                  \
            const int k0_ = s_ * 32 + kq * 8;                                  \
            AV[2 * s_]     = (f32x4){0, 0, 0, 0};                              \
            AV[2 * s_ + 1] = (f32x4){0, 0, 0, 0};                              \
            if (live_) {                                                       \
                if (k0_ + 4 <= DN) AV[2 * s_]     = *(const f32x4*)(fp_ + k0_);\
                if (k0_ + 8 <= DN) AV[2 * s_ + 1] = *(const f32x4*)(fp_ + k0_ + 4); \
            }                                                                  \
        }                                                                      \
    }

#define CSTORE(AV, TILE)                                                       \
    {                                                                          \
        f32x4 acc_[NCT];                                                       \
        _Pragma("unroll")                                                      \
        for (int ct_ = 0; ct_ < NCT; ++ct_) acc_[ct_] = (f32x4){0, 0, 0, 0};   \
        _Pragma("unroll")                                                      \
        for (int s_ = 0; s_ < KSTEPS; ++s_) {                                  \
            bf16x8 a_;                                                         \
            _Pragma("unroll")                                                  \
            for (int j_ = 0; j_ < 4; ++j_) a_[j_]     = f2bf(AV[2 * s_][j_]);  \
            _Pragma("unroll")                                                  \
            for (int j_ = 0; j_ < 4; ++j_) a_[4 + j_] = f2bf(AV[2 * s_ + 1][j_]); \
            _Pragma("unroll")                                                  \
            for (int ct_ = 0; ct_ < NCT; ++ct_) {                              \
                bf16x8 b_ = *(const bf16x8*)&lds_b[((ct_ * KSTEPS + s_) * 64 + lane) * 8]; \
                acc_[ct_] = __builtin_amdgcn_mfma_f32_16x16x32_bf16(a_, b_, acc_[ct_], 0, 0, 0); \
            }                                                                  \
        }                                                                      \
        const int rbase_ = (TILE) * 64 + wv * 16 + (lane >> 4) * 4;            \
        _Pragma("unroll")                                                      \
        for (int rr_ = 0; rr_ < 4; ++rr_) {                                    \
            const int grow_ = rbase_ + rr_;                                    \
            if (grow_ < nrows && ((rowmap == nullptr) || rowmap[grow_])) {     \
                const bool s16_ = (out16 != nullptr) && (srcmap[grow_] != 0);  \
                _Pragma("unroll")                                              \
                for (int ct_ = 0; ct_ < NCT; ++ct_) {                          \
                    const float v_ = acc_[ct_][rr_] + bs[ct_];                 \
                    out8[(size_t)grow_ * DOUT + ct_ * 16 + c0] = f2fp8(v_);    \
                    if (s16_)                                                  \
                        out16[(size_t)grow_ * DOUT + ct_ * 16 + c0] = f2bf(v_);\
                }                                                              \
            }                                                                  \
        }                                                                      \
    }

__global__ __launch_bounds__(256)
void k_proj2(const float* __restrict__ featN, const float* __restrict__ biasN,
             const short* __restrict__ wnF, short* __restrict__ nodeBF,
             unsigned char* __restrict__ nodeF8, const unsigned char* __restrict__ nmap,
             const float* __restrict__ featE, const float* __restrict__ biasE,
             const short* __restrict__ weF, const unsigned char* __restrict__ emap,
             unsigned char* __restrict__ edgeF8)
{
    __shared__ __attribute__((aligned(16))) short lds_b[NCT * KSTEPS * 64 * 8];  // 48 KB
    const int tid = threadIdx.x, lane = tid & 63, wv = tid >> 6;

    const bool edge = (blockIdx.x >= NBLK_N);
    const int  bid  = edge ? blockIdx.x - NBLK_N : blockIdx.x;
    const int  nblk = edge ? NBLK_E : NBLK_N;
    const float* feat = edge ? featE : featN;
    const float* bias = edge ? biasE : biasN;
    const short* wfrag = edge ? weF : wnF;
    const unsigned char* rowmap = edge ? emap : nullptr;
    const unsigned char* srcmap = nmap;
    unsigned char* out8 = edge ? edgeF8 : nodeF8;
    short* out16 = edge ? nullptr : nodeBF;
    const int nrows  = edge ? N_EDGES : N_NODES;
    const int ntiles = (nrows + 63) / 64;

    #pragma unroll
    for (int i = 0; i < 12; ++i)
        ((f32x4*)lds_b)[tid + i * 256] = ((const f32x4*)wfrag)[tid + i * 256];
    __syncthreads();

    const int r15 = lane & 15, kq = lane >> 4, c0 = lane & 15;
    float bs[NCT];
    #pragma unroll
    for (int ct = 0; ct < NCT; ++ct) bs[ct] = bias[ct * 16 + c0];

    int t = bid;
    if (t >= ntiles) return;

    f32x4 avA[2 * KSTEPS], avB[2 * KSTEPS];
    ALOAD(avA, t);
    for (;;) {
        int tn = t + nblk;
        if (tn < ntiles) ALOAD(avB, tn);
        CSTORE(avA, t);
        if (tn >= ntiles) break;
        t = tn;
        tn = t + nblk;
        if (tn < ntiles) ALOAD(avA, tn);
        CSTORE(avB, t);
        if (tn >= ntiles) break;
        t = tn;
    }
}

// ---------------------------------------------------------------------------
// Gather layer. One wave per output row; wave-uniform scalar indices.
// Messages read as fp8 (edge always; node table for L1). Src read bf16.
// L2 neighbor rows come from contiguous bf16 emb1.
// ---------------------------------------------------------------------------
template <bool L2>
__global__ __launch_bounds__(256)
void k_gather(const short* __restrict__ node_bf16, const unsigned char* __restrict__ edge_f8,
              const unsigned char* __restrict__ node_f8, const short* __restrict__ emb1_tab,
              const int* __restrict__ src_idx, const float* __restrict__ ts_arr,
              const int* __restrict__ nbrs, const int* __restrict__ eidx,
              const float* __restrict__ etime,
              const float* __restrict__ bt, const float* __restrict__ tw,
              const float* __restrict__ tp, const float* __restrict__ tconst,
              float* __restrict__ partial_f32, short* __restrict__ partial_bf16,
              short* __restrict__ csum_out)
{
    const int tid = threadIdx.x, lane = tid & 63;
    const int wv  = __builtin_amdgcn_readfirstlane(tid >> 6);
    const int row = blockIdx.x * 4 + wv;

    // wave-uniform index/time loads -> SGPRs
    const int*   np_ = nbrs  + (size_t)row * KNBR;
    const int*   ep_ = eidx  + (size_t)row * KNBR;
    const float* tt_ = etime + (size_t)row * KNBR;
    int   nk[KNBR], ek[KNBR];
    float et[KNBR];
    #pragma unroll
    for (int k = 0; k < KNBR; ++k) {
        nk[k] = __builtin_amdgcn_readfirstlane(np_[k]);
        ek[k] = __builtin_amdgcn_readfirstlane(ep_[k]);
        et[k] = rfl_f(tt_[k]);
    }
    const int si = __builtin_amdgcn_readfirstlane(src_idx[row]);
    const float ts = rfl_f(L2 ? ts_arr[row] : ts_arr[row / KNBR]);

    int cnt = 0;
    #pragma unroll
    for (int k = 0; k < KNBR; ++k) cnt += (nk[k] != 0);

    const int d2 = lane * 2;
    // issue every gather before any compute
    uint32_t ev[KNBR], nv[KNBR];
    #pragma unroll
    for (int k = 0; k < KNBR; ++k)
        ev[k] = *(const uint16_t*)(edge_f8 + (size_t)ek[k] * DOUT + d2);
    #pragma unroll
    for (int k = 0; k < KNBR; ++k) {
        if (L2) nv[k] = *(const uint32_t*)(emb1_tab + ((size_t)row * KNBR + k) * DOUT + d2);
        else    nv[k] = *(const uint16_t*)(node_f8 + (size_t)nk[k] * DOUT + d2);
    }
    const uint32_t sv  = *(const uint32_t*)(node_bf16 + (size_t)si * DOUT + d2);
    const f32x2    bt2 = *(const f32x2*)&bt[d2];
    const f32x2    tc2 = *(const f32x2*)&tconst[d2];

    const float wr0 = tw[lane] * INV2PI;
    float base0 = fmaf(ts, wr0, tp[lane] * INV2PI);
    float wr1 = 0.0f, base1 = 0.0f;
    if (lane < DT - 64) {
        wr1   = tw[64 + lane] * INV2PI;
        base1 = fmaf(ts, wr1, tp[64 + lane] * INV2PI);
    }

    float cs0 = 0, cs1 = 0, ms0 = 0, ms1 = 0;
    #pragma unroll
    for (int k = 0; k < KNBR; ++k) {
        const float w = (nk[k] != 0) ? 1.0f : 0.0f;
        float r0 = fmaf(-et[k], wr0, base0); r0 -= floorf(r0);
        float r1 = fmaf(-et[k], wr1, base1); r1 -= floorf(r1);
        cs0 = fmaf(w, __builtin_amdgcn_cosf(r0), cs0);
        cs1 = fmaf(w, __builtin_amdgcn_cosf(r1), cs1);
        f32x2 e2 = fp8pair(ev[k]);
        float nlo, nhi;
        if (L2) { nlo = bflo(nv[k]); nhi = bfhi(nv[k]); }
        else    { f32x2 n2 = fp8pair(nv[k]); nlo = n2[0]; nhi = n2[1]; }
        ms0 = fmaf(w, e2[0] + nlo, ms0);
        ms1 = fmaf(w, e2[1] + nhi, ms1);
    }

    const float fc  = (float)cnt;
    const float inv = (cnt > 0) ? 1.0f / fc : 1.0f;

    csum_out[(size_t)row * CSW + lane] = f2bf(cs0 * inv);
    if (lane < 48)
        csum_out[(size_t)row * CSW + 64 + lane] = f2bf(lane < DT - 64 ? cs1 * inv : 0.0f);

    const float o0 = bflo(sv) + tc2[0] + (ms0 + fc * bt2[0]) * inv;
    const float o1 = bfhi(sv) + tc2[1] + (ms1 + fc * bt2[1]) * inv;
    if (L2) {
        *(f32x2*)(partial_f32 + (size_t)row * DOUT + d2) = (f32x2){o0, o1};
    } else {
        uint32_t u = (uint32_t)(uint16_t)f2bf(o0) | ((uint32_t)(uint16_t)f2bf(o1) << 16);
        *(uint32_t*)(partial_bf16 + (size_t)row * DOUT + d2) = u;
    }
}

// ---------------------------------------------------------------------------
// Time GEMM: io[row][c] += csum'[row][:] @ W_time[:,c]   (in-place RMW).
// ---------------------------------------------------------------------------
template <bool F32IO>
__global__ __launch_bounds__(256)
void k_tgemm(const short* __restrict__ csum, const short* __restrict__ wtF,
             float* __restrict__ io_f32, short* __restrict__ io_bf16,
             int nrows, int ntiles)
{
    __shared__ __attribute__((aligned(16))) short lds_b[NCT * KSTEPS_T * 64 * 8];  // 32 KB
    const int tid = threadIdx.x, lane = tid & 63, wv = tid >> 6;

    #pragma unroll
    for (int i = 0; i < 8; ++i)
        ((f32x4*)lds_b)[tid + i * 256] = ((const f32x4*)wtF)[tid + i * 256];
    __syncthreads();

    const int r15 = lane & 15, kq = lane >> 4, c0 = lane & 15;

    for (int tile = blockIdx.x; tile < ntiles; tile += gridDim.x) {
        const int row0 = tile * 64 + wv * 16;
        int r = row0 + r15;
        if (r > nrows - 1) r = nrows - 1;
        const short* ap = csum + (size_t)r * CSW;

        f32x4 acc[NCT];
        #pragma unroll
        for (int ct = 0; ct < NCT; ++ct) acc[ct] = (f32x4){0, 0, 0, 0};

        #pragma unroll
        for (int s = 0; s < KSTEPS_T; ++s) {
            const int k0 = s * 32 + kq * 8;
            bf16x8 a = (bf16x8)(short)0;
            if (k0 + 8 <= CSW) a = *(const bf16x8*)(ap + k0);
            #pragma unroll
            for (int ct = 0; ct < NCT; ++ct) {
                bf16x8 b = *(const bf16x8*)&lds_b[((ct * KSTEPS_T + s) * 64 + lane) * 8];
                acc[ct] = __builtin_amdgcn_mfma_f32_16x16x32_bf16(a, b, acc[ct], 0, 0, 0);
            }
        }
        const int rbase = row0 + (lane >> 4) * 4;
        #pragma unroll
        for (int ct = 0; ct < NCT; ++ct) {
            const int c = ct * 16 + c0;
            #pragma unroll
            for (int rr = 0; rr < 4; ++rr) {
                int grow = rbase + rr;
                if (grow < nrows) {
                    size_t off = (size_t)grow * DOUT + c;
                    if (F32IO) {
                        io_f32[off] += acc[ct][rr];
                    } else {
                        float oldv = bflo((uint32_t)(uint16_t)io_bf16[off]);
                        io_bf16[off] = f2bf(oldv + acc[ct][rr]);
                    }
                }
            }
        }
    }
}

// ---------------------------------------------------------------------------
extern "C" void kernel_launch(void* const* d_in, const int* in_sizes, int n_in,
                              void* d_out, int out_size, void* d_ws, size_t ws_size,
                              hipStream_t stream)
{
    const float* node_features = (const float*)d_in[0];
    const float* edge_features = (const float*)d_in[1];
    const float* W_node  = (const float*)d_in[2];
    const float* b_node  = (const float*)d_in[3];
    const float* W_time  = (const float*)d_in[4];
    const float* b_time  = (const float*)d_in[5];
    const float* W_edge  = (const float*)d_in[6];
    const float* b_edge  = (const float*)d_in[7];
    const float* time_w  = (const float*)d_in[8];
    const float* time_ph = (const float*)d_in[9];
    const int*   source_nodes = (const int*)d_in[10];
    const float* timestamps   = (const float*)d_in[11];
    const int*   nbrs_l2  = (const int*)d_in[12];
    const int*   eidx_l2  = (const int*)d_in[13];
    const float* etime_l2 = (const float*)d_in[14];
    const int*   nbrs_l1  = (const int*)d_in[15];
    const int*   eidx_l1  = (const int*)d_in[16];
    const float* etime_l1 = (const float*)d_in[17];

    // workspace layout (all offsets 256B-aligned)
    char*  ws        = (char*)d_ws;
    short* node_bf16 = (short*)(ws);                        // 128,000,000
    unsigned char* edge_f8 = (unsigned char*)(ws + 128000000);  // 128,000,000
    unsigned char* node_f8 = (unsigned char*)(ws + 256000000);  //  64,000,000
    short* emb1      = (short*)(ws + 320000000);            //  20,971,520 (bf16)
    short* csum1     = (short*)(ws + 340971520);            //  18,350,080
    short* csum2     = (short*)(ws + 359321600);            //     917,504
    float* tconst    = (float*)(ws + 360239104);            //         512
    short* wnF       = (short*)(ws + 360239616);            //      49,152
    short* weF       = (short*)(ws + 360288768);            //      49,152
    short* wtF       = (short*)(ws + 360337920);            //      32,768
    unsigned char* emap = (unsigned char*)(ws + 360371200); //   1,000,000
    unsigned char* nmap = (unsigned char*)(ws + 361371200); //     500,224 -> 361,871,424
    if (ws_size < 362000000ull) return;

    hipMemsetAsync(emap, 0, N_EDGES + 500224, stream);   // emap + nmap contiguous

    k_prep<<<577, 256, 0, stream>>>(W_node, W_edge, W_time, b_time, time_ph,
                                    eidx_l1, eidx_l2, nbrs_l2, source_nodes,
                                    wnF, weF, wtF, tconst, emap, nmap);

    k_proj2<<<NBLK_N + NBLK_E, 256, 0, stream>>>(
        node_features, b_node, wnF, node_bf16, node_f8, nmap,
        edge_features, b_edge, weF, emap, edge_f8);

    // layer 1: rows = B*K; fp8 msg gathers; partial -> emb1 (bf16)
    k_gather<false><<<(BATCH * KNBR) / 4, 256, 0, stream>>>(
        node_bf16, edge_f8, node_f8, emb1, nbrs_l2,
        timestamps, nbrs_l1, eidx_l1, etime_l1,
        b_time, time_w, time_ph, tconst,
        nullptr, emb1, csum1);
    {
        int nt = (BATCH * KNBR + 63) / 64;
        k_tgemm<false><<<nt, 256, 0, stream>>>(csum1, wtF, nullptr, emb1, BATCH * KNBR, nt);
    }

    // layer 2: rows = B; edge fp8 + emb1 bf16; partial -> d_out (f32)
    k_gather<true><<<BATCH / 4, 256, 0, stream>>>(
        node_bf16, edge_f8, node_f8, emb1, source_nodes,
        timestamps, nbrs_l2, eidx_l2, etime_l2,
        b_time, time_w, time_ph, tconst,
        (float*)d_out, nullptr, csum2);
    {
        int nt = (BATCH + 63) / 64;
        k_tgemm<true><<<nt, 256, 0, stream>>>(csum2, wtF, (float*)d_out, nullptr, BATCH, nt);
    }
}